// Round 3
// baseline (4769.346 us; speedup 1.0000x reference)
//
#include <hip/hip_runtime.h>
#include <hip/hip_bf16.h>
#include <cstdint>
#include <cstddef>

// Cross_attention_dl: B=4, S=2048, D1=512, D2=1024. ALL I/O float32.
// Sharp softmax (no 1/sqrt(d)) makes logits ~N(0,22..72); to match the f32
// reference within 2% absmax, every GEMM feeding logits runs in split-bf16
// (hi/lo, 3 MFMA planes => per-term rel err ~2^-18). Intermediates all f32.
// split=1 (plain bf16) only for stage-2 V-proj and stage-2 P@V (output-only).

typedef __bf16 bf16;
typedef __attribute__((ext_vector_type(8))) __bf16 bf16x8;
typedef __attribute__((ext_vector_type(4))) __bf16 bf16x4;
typedef __attribute__((ext_vector_type(4))) float f32x4;

#define TM 128
#define TN 128
#define TK 32            // K-tile in ORIGINAL (f32) elements
#define LK 104           // LDS row: 3 planes * 32 + 8 pad; 208 B = 13*16 (16B-aligned rows)

// C[m,n] = sum_k A[m,k]*B[n,k], A/B/C f32. Split staging:
//   plane0 = A_hi, plane1 = A_lo, plane2 = A_hi   (A side)
//   plane0 = B_hi, plane1 = B_hi, plane2 = B_lo   (B side)
// => hi*hi + lo*hi + hi*lo accumulated over split planes.
// mode 0: C[m][n] = acc + bias[n] + resid[m][n]*scale
// mode 2: C[n][m] = acc + bias[n]   (transposed store, for V^T)
__global__ __launch_bounds__(256) void gemm_nt_split(
    const float* __restrict__ A, int lda,
    const float* __restrict__ B, int ldb,
    float* __restrict__ C, int ldc, int mode,
    const float* __restrict__ bias,
    const float* __restrict__ resid, int ldr,
    const float* __restrict__ scale,
    int K, int split)
{
    __shared__ __align__(16) bf16 As[TM][LK];
    __shared__ __align__(16) bf16 Bs[TN][LK];

    const int t    = threadIdx.x;
    const int wave = t >> 6;
    const int lane = t & 63;
    const int wr   = wave >> 1;
    const int wc   = wave & 1;
    const int r16  = lane & 15;
    const int quad = lane >> 4;

    const int row0 = blockIdx.y * TM;
    const int col0 = blockIdx.x * TN;

    f32x4 acc[4][4];
#pragma unroll
    for (int r = 0; r < 4; ++r)
#pragma unroll
        for (int c = 0; c < 4; ++c)
            acc[r][c] = (f32x4){0.f, 0.f, 0.f, 0.f};

    for (int kt = 0; kt < K; kt += TK) {
        // stage 128x32 f32 of A and B, split into bf16 hi/lo planes
#pragma unroll
        for (int p = 0; p < 4; ++p) {
            int idx = t + p * 256;
            int r   = idx >> 3;         // 0..127
            int c   = (idx & 7) * 4;    // 0..28
            f32x4 va = *reinterpret_cast<const f32x4*>(A + (long)(row0 + r) * lda + kt + c);
            f32x4 vb = *reinterpret_cast<const f32x4*>(B + (long)(col0 + r) * ldb + kt + c);
            bf16x4 ah, al, bh, bl;
#pragma unroll
            for (int i = 0; i < 4; ++i) {
                bf16 h = (bf16)va[i];
                ah[i] = h;
                al[i] = (bf16)(va[i] - (float)h);
                bf16 g = (bf16)vb[i];
                bh[i] = g;
                bl[i] = (bf16)(vb[i] - (float)g);
            }
            *reinterpret_cast<bf16x4*>(&As[r][c]) = ah;
            *reinterpret_cast<bf16x4*>(&Bs[r][c]) = bh;
            if (split == 3) {
                *reinterpret_cast<bf16x4*>(&As[r][32 + c]) = al;   // A_lo
                *reinterpret_cast<bf16x4*>(&As[r][64 + c]) = ah;   // A_hi again
                *reinterpret_cast<bf16x4*>(&Bs[r][32 + c]) = bh;   // B_hi again
                *reinterpret_cast<bf16x4*>(&Bs[r][64 + c]) = bl;   // B_lo
            }
        }
        __syncthreads();
        for (int s = 0; s < split; ++s) {
            const int kk = s * 32;
            bf16x8 af[4], bfr[4];
#pragma unroll
            for (int r = 0; r < 4; ++r)
                af[r] = *reinterpret_cast<const bf16x8*>(&As[wr * 64 + r * 16 + r16][kk + quad * 8]);
#pragma unroll
            for (int c = 0; c < 4; ++c)
                bfr[c] = *reinterpret_cast<const bf16x8*>(&Bs[wc * 64 + c * 16 + r16][kk + quad * 8]);
#pragma unroll
            for (int r = 0; r < 4; ++r)
#pragma unroll
                for (int c = 0; c < 4; ++c)
                    acc[r][c] = __builtin_amdgcn_mfma_f32_16x16x32_bf16(af[r], bfr[c], acc[r][c], 0, 0, 0);
        }
        __syncthreads();
    }

    float sc = 0.f;
    if (resid) sc = *scale;

#pragma unroll
    for (int r = 0; r < 4; ++r) {
#pragma unroll
        for (int c = 0; c < 4; ++c) {
            int gcol = col0 + wc * 64 + c * 16 + r16;
            float bv = bias ? bias[gcol] : 0.f;
#pragma unroll
            for (int i = 0; i < 4; ++i) {
                int grow = row0 + wr * 64 + r * 16 + quad * 4 + i;
                float v = acc[r][c][i] + bv;
                if (mode == 2) {
                    C[(long)gcol * ldc + grow] = v;
                } else {
                    if (resid) v += resid[(long)grow * ldr + gcol] * sc;
                    C[(long)grow * ldc + gcol] = v;
                }
            }
        }
    }
}

// In-place f32 row softmax over 2048 cols. One block (256 thr) per row.
__global__ __launch_bounds__(256) void softmax_kernel(float* __restrict__ S)
{
    __shared__ float redm[4], reds[4];
    float* srow = S + (long)blockIdx.x * 2048;
    const int t = threadIdx.x;
    const int lane = t & 63;
    const int wave = t >> 6;

    f32x4 v0 = *reinterpret_cast<const f32x4*>(srow + t * 4);
    f32x4 v1 = *reinterpret_cast<const f32x4*>(srow + 1024 + t * 4);

    float m = v0[0];
#pragma unroll
    for (int i = 1; i < 4; ++i) m = fmaxf(m, v0[i]);
#pragma unroll
    for (int i = 0; i < 4; ++i) m = fmaxf(m, v1[i]);
#pragma unroll
    for (int off = 32; off > 0; off >>= 1) m = fmaxf(m, __shfl_xor(m, off));
    if (lane == 0) redm[wave] = m;
    __syncthreads();
    m = fmaxf(fmaxf(redm[0], redm[1]), fmaxf(redm[2], redm[3]));

    float s = 0.f;
#pragma unroll
    for (int i = 0; i < 4; ++i) { v0[i] = __expf(v0[i] - m); s += v0[i]; }
#pragma unroll
    for (int i = 0; i < 4; ++i) { v1[i] = __expf(v1[i] - m); s += v1[i]; }
#pragma unroll
    for (int off = 32; off > 0; off >>= 1) s += __shfl_xor(s, off);
    if (lane == 0) reds[wave] = s;
    __syncthreads();
    s = reds[0] + reds[1] + reds[2] + reds[3];
    float inv = 1.f / s;

#pragma unroll
    for (int i = 0; i < 4; ++i) { v0[i] *= inv; v1[i] *= inv; }
    *reinterpret_cast<f32x4*>(srow + t * 4) = v0;
    *reinterpret_cast<f32x4*>(srow + 1024 + t * 4) = v1;
}

extern "C" void kernel_launch(void* const* d_in, const int* in_sizes, int n_in,
                              void* d_out, int out_size, void* d_ws, size_t ws_size,
                              hipStream_t stream)
{
    const float* x   = (const float*)d_in[0];
    const float* y   = (const float*)d_in[1];
    const float* Wq1 = (const float*)d_in[2];
    const float* bq1 = (const float*)d_in[3];
    const float* Wk1 = (const float*)d_in[4];
    const float* bk1 = (const float*)d_in[5];
    const float* Wv1 = (const float*)d_in[6];
    const float* bv1 = (const float*)d_in[7];
    const float* Wq2 = (const float*)d_in[8];
    const float* bq2 = (const float*)d_in[9];
    const float* Wk2 = (const float*)d_in[10];
    const float* bk2 = (const float*)d_in[11];
    const float* Wv2 = (const float*)d_in[12];
    const float* bv2 = (const float*)d_in[13];
    const float* w1  = (const float*)d_in[14];
    const float* w2  = (const float*)d_in[15];
    float* out = (float*)d_out;

    // Workspace (all f32, 72 MB total):
    //   temp [8192][1024] = 32 MB   (concat(x1,y1), feeds stage 2)
    //   qf   [2048][1024] =  8 MB   (per-batch Q)
    //   kf   [2048][1024] =  8 MB   (per-batch K)
    //   vTf  [1024][2048] =  8 MB   (per-batch V^T)
    //   Sc   [2048][2048] = 16 MB   (per-batch scores; softmax in place)
    char* ws = (char*)d_ws;
    float* temp = (float*)ws;
    float* qf   = (float*)(ws + 33554432L);
    float* kf   = (float*)(ws + 33554432L + 8388608L);
    float* vTf  = (float*)(ws + 33554432L + 2 * 8388608L);
    float* Sc   = (float*)(ws + 33554432L + 3 * 8388608L);

    auto gemm = [&](const float* A, int lda, const float* B, int ldb,
                    float* C, int ldc, int mode, const float* bias,
                    const float* resid, int ldr, const float* scale,
                    int M, int N, int K, int split) {
        dim3 g(N / TN, M / TM, 1);
        gemm_nt_split<<<g, dim3(256), 0, stream>>>(A, lda, B, ldb, C, ldc, mode,
                                                   bias, resid, ldr, scale, K, split);
    };

    // One self-attention over src [4][2048][D] with square weights [D][D].
    // dst rows at stride ldd (+ optional col offset baked into dst pointer);
    // resid (optional) [4][2048][ldr] scaled by *scale.
    // logit_path: stage-1 => everything split=3; final stage => V/PV split=1.
    auto attn = [&](const float* src, int D,
                    const float* Wq, const float* bq, const float* Wk, const float* bk,
                    const float* Wv, const float* bv,
                    float* dst, int ldd, const float* resid, int ldr, const float* scale,
                    int pv_split) {
        for (int b = 0; b < 4; ++b) {
            const float* s = src + (long)b * 2048 * D;
            gemm(s, D, Wq, D, qf, D, 0, bq, nullptr, 0, nullptr, 2048, D, D, 3);
            gemm(s, D, Wk, D, kf, D, 0, bk, nullptr, 0, nullptr, 2048, D, D, 3);
            gemm(s, D, Wv, D, vTf, 2048, 2, bv, nullptr, 0, nullptr, 2048, D, D, pv_split);
            // scores: [2048][2048] = qf @ kf^T (split for logit accuracy)
            gemm(qf, D, kf, D, Sc, 2048, 0, nullptr, nullptr, 0, nullptr, 2048, 2048, D, 3);
            softmax_kernel<<<dim3(2048), dim3(256), 0, stream>>>(Sc);
            // out rows: P @ V^T
            gemm(Sc, 2048, vTf, 2048, dst + (long)b * 2048 * ldd, ldd, 0, nullptr,
                 resid ? resid + (long)b * 2048 * ldr : nullptr, ldr, scale,
                 2048, D, 2048, pv_split);
        }
    };

    // stage 1: x1 = attn(x)+y*w2 -> temp[:, :512]; y1 = attn(y)+x*w1 -> temp[:, 512:]
    attn(x, 512, Wq1, bq1, Wk1, bk1, Wv1, bv1, temp,       1024, y, 512, w2, 3);
    attn(y, 512, Wq1, bq1, Wk1, bk1, Wv1, bv1, temp + 512, 1024, x, 512, w1, 3);
    // stage 2: out = attn(temp) with D2=1024 weights; PV/V-proj feed output only
    attn(temp, 1024, Wq2, bq2, Wk2, bk2, Wv2, bv2, out, 1024, nullptr, 0, nullptr, 1);

    (void)in_sizes; (void)n_in; (void)out_size; (void)ws_size;
}

// Round 4
// 1349.472 us; speedup vs baseline: 3.5342x; 3.5342x over previous
//
#include <hip/hip_runtime.h>
#include <hip/hip_bf16.h>
#include <cstdint>
#include <cstddef>

// Cross_attention_dl: B=4, S=2048, D1=512, D2=1024. ALL I/O f32.
// Split-precision (bf16 hi/lo plane) MFMA pipeline. All GEMM operands live in
// global memory as pre-split bf16 planes; split-3 GEMM = 3 plain bf16 K-loop
// phases (Ah*Bh + Al*Bh + Ah*Bl). K-loop uses m97 structure: global_load_lds
// width-16 into unpadded [128][64] LDS tiles, ds_read_b128 fragments.

typedef __bf16 bf16;
typedef __attribute__((ext_vector_type(8))) __bf16 bf16x8;
typedef __attribute__((ext_vector_type(4))) __bf16 bf16x4;
typedef __attribute__((ext_vector_type(4))) float f32x4;

__device__ __forceinline__ void gld16(const bf16* g, bf16* s) {
    __builtin_amdgcn_global_load_lds(
        (const __attribute__((address_space(1))) void*)g,
        (__attribute__((address_space(3))) void*)s, 16, 0, 0);
}

// C = A @ B^T over bf16 planes. All strides in ELEMENTS.
// split=3: phases (A0,B0),(A1,B0),(A0,B1); split=1: (A0,B0) only.
// mode 0: f32 C[z][m][n] = acc (+resid*scale)
// mode 1: bf16 plane-pair row-major: C[p][z*M+m][n] = acc + bias[n] (+resid*scale)
// mode 2: bf16 plane-pair transposed: C[b][p][n][s] (b=grow>>11, s=grow&2047) = acc + bias[n]
__global__ __launch_bounds__(256) void gemm_split(
    const bf16* __restrict__ A, long lda, long psA, long bsA,
    const bf16* __restrict__ B, long ldb, long psB, long bsB,
    void* __restrict__ C, long ldc, long psC, long bsC, int mode,
    const float* __restrict__ bias,
    const float* __restrict__ resid, long ldr, long bsR,
    const float* __restrict__ scale,
    int K, int split)
{
    __shared__ __align__(16) bf16 As[128][64];
    __shared__ __align__(16) bf16 Bs[128][64];

    const int t    = threadIdx.x;
    const int wave = t >> 6;
    const int lane = t & 63;
    const int wr   = wave >> 1;
    const int wc   = wave & 1;
    const int r16  = lane & 15;
    const int quad = lane >> 4;

    const long row0 = (long)blockIdx.y * 128;
    const long col0 = (long)blockIdx.x * 128;
    const long z    = blockIdx.z;

    const int srow = (lane >> 3);        // 0..7 within an 8-row chunk
    const int scol = (lane & 7) * 8;     // element col of this lane's 16B

    f32x4 acc[4][4];
#pragma unroll
    for (int r = 0; r < 4; ++r)
#pragma unroll
        for (int c = 0; c < 4; ++c)
            acc[r][c] = (f32x4){0.f, 0.f, 0.f, 0.f};

    for (int ph = 0; ph < split; ++ph) {
        const bf16* Ab = A + z * bsA + (ph == 1 ? psA : 0);
        const bf16* Bb = B + z * bsB + (ph == 2 ? psB : 0);
        for (int kt = 0; kt < K; kt += 64) {
#pragma unroll
            for (int p = 0; p < 4; ++p) {
                const int chunk = wave * 32 + p * 8;   // 8 rows per 1KB wave store
                gld16(Ab + (row0 + chunk + srow) * lda + kt + scol, &As[chunk][0]);
                gld16(Bb + (col0 + chunk + srow) * ldb + kt + scol, &Bs[chunk][0]);
            }
            __syncthreads();
#pragma unroll
            for (int kk = 0; kk < 64; kk += 32) {
                bf16x8 af[4], bg[4];
#pragma unroll
                for (int r = 0; r < 4; ++r)
                    af[r] = *reinterpret_cast<const bf16x8*>(&As[wr * 64 + r * 16 + r16][kk + quad * 8]);
#pragma unroll
                for (int c = 0; c < 4; ++c)
                    bg[c] = *reinterpret_cast<const bf16x8*>(&Bs[wc * 64 + c * 16 + r16][kk + quad * 8]);
#pragma unroll
                for (int r = 0; r < 4; ++r)
#pragma unroll
                    for (int c = 0; c < 4; ++c)
                        acc[r][c] = __builtin_amdgcn_mfma_f32_16x16x32_bf16(af[r], bg[c], acc[r][c], 0, 0, 0);
            }
            __syncthreads();
        }
    }

    const float scv = resid ? *scale : 0.f;

#pragma unroll
    for (int r = 0; r < 4; ++r) {
#pragma unroll
        for (int c = 0; c < 4; ++c) {
            long gcol = col0 + wc * 64 + c * 16 + r16;
            float bv = bias ? bias[gcol] : 0.f;
#pragma unroll
            for (int i = 0; i < 4; ++i) {
                long grow = row0 + wr * 64 + r * 16 + quad * 4 + i;
                float val = acc[r][c][i] + bv;
                if (mode == 0) {
                    if (resid) val += resid[z * bsR + grow * ldr + gcol] * scv;
                    ((float*)C)[z * bsC + grow * ldc + gcol] = val;
                } else if (mode == 1) {
                    if (resid) val += resid[z * bsR + grow * ldr + gcol] * scv;
                    bf16* Cb = (bf16*)C + z * bsC;
                    bf16 h = (bf16)val;
                    Cb[grow * ldc + gcol] = h;
                    Cb[psC + grow * ldc + gcol] = (bf16)(val - (float)h);
                } else {
                    long b = grow >> 11, s = grow & 2047;
                    bf16* Cb = (bf16*)C + b * bsC;
                    bf16 h = (bf16)val;
                    Cb[gcol * ldc + s] = h;
                    Cb[psC + gcol * ldc + s] = (bf16)(val - (float)h);
                }
            }
        }
    }
}

// Row softmax over 2048 f32 cols; writes P IN PLACE as bf16 hi plane (cols
// [0,2048) of the row's 4096 bf16 slots) and lo plane (cols [2048,4096)).
__global__ __launch_bounds__(256) void softmax_planes(float* __restrict__ S)
{
    __shared__ float redm[4], reds[4];
    float* srow = S + (long)blockIdx.x * 2048;
    const int t = threadIdx.x;
    const int lane = t & 63;
    const int wave = t >> 6;

    f32x4 v0 = *reinterpret_cast<const f32x4*>(srow + t * 4);
    f32x4 v1 = *reinterpret_cast<const f32x4*>(srow + 1024 + t * 4);

    float m = v0[0];
#pragma unroll
    for (int i = 1; i < 4; ++i) m = fmaxf(m, v0[i]);
#pragma unroll
    for (int i = 0; i < 4; ++i) m = fmaxf(m, v1[i]);
#pragma unroll
    for (int off = 32; off > 0; off >>= 1) m = fmaxf(m, __shfl_xor(m, off));
    if (lane == 0) redm[wave] = m;
    __syncthreads();
    m = fmaxf(fmaxf(redm[0], redm[1]), fmaxf(redm[2], redm[3]));

    float s = 0.f;
#pragma unroll
    for (int i = 0; i < 4; ++i) { v0[i] = __expf(v0[i] - m); s += v0[i]; }
#pragma unroll
    for (int i = 0; i < 4; ++i) { v1[i] = __expf(v1[i] - m); s += v1[i]; }
#pragma unroll
    for (int off = 32; off > 0; off >>= 1) s += __shfl_xor(s, off);
    if (lane == 0) reds[wave] = s;
    __syncthreads();
    s = reds[0] + reds[1] + reds[2] + reds[3];
    float inv = 1.f / s;

    bf16x4 h0, h1, l0, l1;
#pragma unroll
    for (int i = 0; i < 4; ++i) {
        float a = v0[i] * inv, b = v1[i] * inv;
        h0[i] = (bf16)a; l0[i] = (bf16)(a - (float)h0[i]);
        h1[i] = (bf16)b; l1[i] = (bf16)(b - (float)h1[i]);
    }
    bf16* ph = (bf16*)srow;
    *reinterpret_cast<bf16x4*>(ph + t * 4) = h0;
    *reinterpret_cast<bf16x4*>(ph + 1024 + t * 4) = h1;
    *reinterpret_cast<bf16x4*>(ph + 2048 + t * 4) = l0;
    *reinterpret_cast<bf16x4*>(ph + 3072 + t * 4) = l1;
}

// f32[n] -> hi bf16[n], lo bf16[n] (lo plane at hi+n). n % 1024 == 0.
__global__ __launch_bounds__(256) void split_f32(
    const float* __restrict__ in, bf16* __restrict__ hi, long n)
{
    long i = ((long)blockIdx.x * 256 + threadIdx.x) * 4;
    f32x4 v = *reinterpret_cast<const f32x4*>(in + i);
    bf16x4 h, l;
#pragma unroll
    for (int j = 0; j < 4; ++j) {
        h[j] = (bf16)v[j];
        l[j] = (bf16)(v[j] - (float)h[j]);
    }
    *reinterpret_cast<bf16x4*>(hi + i) = h;
    *reinterpret_cast<bf16x4*>(hi + n + i) = l;
}

extern "C" void kernel_launch(void* const* d_in, const int* in_sizes, int n_in,
                              void* d_out, int out_size, void* d_ws, size_t ws_size,
                              hipStream_t stream)
{
    const float* x   = (const float*)d_in[0];
    const float* y   = (const float*)d_in[1];
    const float* Wq1 = (const float*)d_in[2];
    const float* bq1 = (const float*)d_in[3];
    const float* Wk1 = (const float*)d_in[4];
    const float* bk1 = (const float*)d_in[5];
    const float* Wv1 = (const float*)d_in[6];
    const float* bv1 = (const float*)d_in[7];
    const float* Wq2 = (const float*)d_in[8];
    const float* bq2 = (const float*)d_in[9];
    const float* Wk2 = (const float*)d_in[10];
    const float* bk2 = (const float*)d_in[11];
    const float* Wv2 = (const float*)d_in[12];
    const float* bv2 = (const float*)d_in[13];
    const float* w1  = (const float*)d_in[14];
    const float* w2  = (const float*)d_in[15];
    float* out = (float*)d_out;

    const size_t MB = 1ull << 20;
    char* ws = (char*)d_ws;
    const long S = 2048, M4 = 8192, E1 = 512, E2 = 1024;
    const long W1ps = E1 * E1, W2ps = E2 * E2;

    // cfg 2 (ws >= 207MB): z=4-batched scores/softmax/PV, batched projections.
    // cfg 0 (75MB): per-batch pipeline; W2 planes staged in d_out after stage 1.
    const int cfg = (ws_size >= 207 * MB) ? 2 : 0;

    bf16 *Wq1p, *Wk1p, *Wv1p, *Wq2p, *Wk2p, *Wv2p, *temp, *qb, *kb, *vt;
    float* Sc;
    bf16* xp = (bf16*)d_out;             // [2][8192][512] planes (16MB), dead after stage-1 proj
    bf16* yp = xp + 2 * M4 * E1;         // next 16MB of d_out
    if (cfg == 2) {
        Wq1p = (bf16*)(ws + 0 * MB);  Wk1p = (bf16*)(ws + 1 * MB);  Wv1p = (bf16*)(ws + 2 * MB);
        Wq2p = (bf16*)(ws + 3 * MB);  Wk2p = (bf16*)(ws + 7 * MB);  Wv2p = (bf16*)(ws + 11 * MB);
        temp = (bf16*)(ws + 15 * MB);                 // [2][8192][1024] 32MB
        qb   = (bf16*)(ws + 47 * MB);                 // [2][8192][E]   32MB
        kb   = (bf16*)(ws + 79 * MB);
        vt   = (bf16*)(ws + 111 * MB);                // [4][2][E][2048] 32MB
        Sc   = (float*)(ws + 143 * MB);               // [4][2048][2048] 64MB
    } else {
        Wq1p = (bf16*)(ws + 0 * MB);  Wk1p = (bf16*)(ws + 1 * MB);  Wv1p = (bf16*)(ws + 2 * MB);
        temp = (bf16*)(ws + 3 * MB);                  // 32MB
        qb   = (bf16*)(ws + 35 * MB);                 // [2][2048][E] 8MB
        kb   = (bf16*)(ws + 43 * MB);
        vt   = (bf16*)(ws + 51 * MB);                 // [2][E][2048] 8MB
        Sc   = (float*)(ws + 59 * MB);                // [2048][2048] 16MB
        Wq2p = (bf16*)d_out;                          // staged after stage 1 (xp dead)
        Wk2p = Wq2p + 2 * W2ps;
        Wv2p = Wk2p + 2 * W2ps;
    }

    auto gemm = [&](const bf16* A, long lda, long psA, long bsA,
                    const bf16* B, long ldb, long psB, long bsB,
                    void* C, long ldc, long psC, long bsC, int mode,
                    const float* bias, const float* resid, long ldr, long bsR,
                    const float* scale, int M, int N, int K, int split, int gz) {
        gemm_split<<<dim3(N / 128, M / 128, gz), dim3(256), 0, stream>>>(
            A, lda, psA, bsA, B, ldb, psB, bsB, C, ldc, psC, bsC, mode,
            bias, resid, ldr, bsR, scale, K, split);
    };
    auto conv = [&](const float* in, bf16* planes, long n) {
        split_f32<<<dim3((unsigned)(n / 1024)), dim3(256), 0, stream>>>(in, planes, n);
    };

    conv(x, xp, M4 * E1);
    conv(y, yp, M4 * E1);
    conv(Wq1, Wq1p, W1ps); conv(Wk1, Wk1p, W1ps); conv(Wv1, Wv1p, W1ps);
    if (cfg == 2) { conv(Wq2, Wq2p, W2ps); conv(Wk2, Wk2p, W2ps); conv(Wv2, Wv2p, W2ps); }

    // stage-1 attention (D=E=512) for one path; writes temp[:, colOff:colOff+512]
    auto stage1 = [&](const bf16* sp, const float* resid, const float* scale, long colOff) {
        if (cfg == 2) {
            gemm(sp, E1, M4 * E1, 0, Wq1p, E1, W1ps, 0, qb, E1, M4 * E1, 0, 1,
                 bq1, nullptr, 0, 0, nullptr, 8192, 512, 512, 3, 1);
            gemm(sp, E1, M4 * E1, 0, Wk1p, E1, W1ps, 0, kb, E1, M4 * E1, 0, 1,
                 bk1, nullptr, 0, 0, nullptr, 8192, 512, 512, 3, 1);
            gemm(sp, E1, M4 * E1, 0, Wv1p, E1, W1ps, 0, vt, S, E1 * S, 2 * E1 * S, 2,
                 bv1, nullptr, 0, 0, nullptr, 8192, 512, 512, 3, 1);
            gemm(qb, E1, M4 * E1, S * E1, kb, E1, M4 * E1, S * E1, Sc, S, 0, S * S, 0,
                 nullptr, nullptr, 0, 0, nullptr, 2048, 2048, 512, 3, 4);
            softmax_planes<<<dim3(8192), dim3(256), 0, stream>>>(Sc);
            gemm((const bf16*)Sc, 4096, 2048, S * 4096, vt, S, E1 * S, 2 * E1 * S,
                 temp + colOff, 1024, M4 * 1024, S * 1024, 1,
                 nullptr, resid, E1, S * E1, scale, 2048, 512, 2048, 3, 4);
        } else {
            for (int b = 0; b < 4; ++b) {
                const bf16* sb = sp + (long)b * S * E1;
                gemm(sb, E1, M4 * E1, 0, Wq1p, E1, W1ps, 0, qb, E1, S * E1, 0, 1,
                     bq1, nullptr, 0, 0, nullptr, 2048, 512, 512, 3, 1);
                gemm(sb, E1, M4 * E1, 0, Wk1p, E1, W1ps, 0, kb, E1, S * E1, 0, 1,
                     bk1, nullptr, 0, 0, nullptr, 2048, 512, 512, 3, 1);
                gemm(sb, E1, M4 * E1, 0, Wv1p, E1, W1ps, 0, vt, S, E1 * S, 0, 2,
                     bv1, nullptr, 0, 0, nullptr, 2048, 512, 512, 3, 1);
                gemm(qb, E1, S * E1, 0, kb, E1, S * E1, 0, Sc, S, 0, 0, 0,
                     nullptr, nullptr, 0, 0, nullptr, 2048, 2048, 512, 3, 1);
                softmax_planes<<<dim3(2048), dim3(256), 0, stream>>>(Sc);
                gemm((const bf16*)Sc, 4096, 2048, 0, vt, S, E1 * S, 0,
                     temp + colOff + (long)b * S * 1024, 1024, M4 * 1024, 0, 1,
                     nullptr, resid + (long)b * S * E1, E1, 0, scale, 2048, 512, 2048, 3, 1);
            }
        }
    };

    stage1(xp, y, w2, 0);     // x1 = attn(x) + y*weight2
    stage1(yp, x, w1, 512);   // y1 = attn(y) + x*weight1

    if (cfg == 0) { conv(Wq2, Wq2p, W2ps); conv(Wk2, Wk2p, W2ps); conv(Wv2, Wv2p, W2ps); }

    // stage-2 attention over temp (D=E=1024) -> out
    if (cfg == 2) {
        gemm(temp, E2, M4 * E2, 0, Wq2p, E2, W2ps, 0, qb, E2, M4 * E2, 0, 1,
             bq2, nullptr, 0, 0, nullptr, 8192, 1024, 1024, 3, 1);
        gemm(temp, E2, M4 * E2, 0, Wk2p, E2, W2ps, 0, kb, E2, M4 * E2, 0, 1,
             bk2, nullptr, 0, 0, nullptr, 8192, 1024, 1024, 3, 1);
        gemm(temp, E2, M4 * E2, 0, Wv2p, E2, W2ps, 0, vt, S, E2 * S, 2 * E2 * S, 2,
             bv2, nullptr, 0, 0, nullptr, 8192, 1024, 1024, 1, 1);
        gemm(qb, E2, M4 * E2, S * E2, kb, E2, M4 * E2, S * E2, Sc, S, 0, S * S, 0,
             nullptr, nullptr, 0, 0, nullptr, 2048, 2048, 1024, 3, 4);
        softmax_planes<<<dim3(8192), dim3(256), 0, stream>>>(Sc);
        gemm((const bf16*)Sc, 4096, 2048, S * 4096, vt, S, E2 * S, 2 * E2 * S,
             out, E2, 0, S * E2, 0, nullptr, nullptr, 0, 0, nullptr,
             2048, 1024, 2048, 1, 4);
    } else {
        for (int b = 0; b < 4; ++b) {
            const bf16* tb = temp + (long)b * S * E2;
            gemm(tb, E2, M4 * E2, 0, Wq2p, E2, W2ps, 0, qb, E2, S * E2, 0, 1,
                 bq2, nullptr, 0, 0, nullptr, 2048, 1024, 1024, 3, 1);
            gemm(tb, E2, M4 * E2, 0, Wk2p, E2, W2ps, 0, kb, E2, S * E2, 0, 1,
                 bk2, nullptr, 0, 0, nullptr, 2048, 1024, 1024, 3, 1);
            gemm(tb, E2, M4 * E2, 0, Wv2p, E2, W2ps, 0, vt, S, E2 * S, 0, 2,
                 bv2, nullptr, 0, 0, nullptr, 2048, 1024, 1024, 1, 1);
            gemm(qb, E2, S * E2, 0, kb, E2, S * E2, 0, Sc, S, 0, 0, 0,
                 nullptr, nullptr, 0, 0, nullptr, 2048, 2048, 1024, 3, 1);
            softmax_planes<<<dim3(2048), dim3(256), 0, stream>>>(Sc);
            gemm((const bf16*)Sc, 4096, 2048, 0, vt, S, E2 * S, 0,
                 out + (long)b * S * E2, E2, 0, 0, 0, nullptr, nullptr, 0, 0, nullptr,
                 2048, 1024, 2048, 1, 1);
        }
    }

    (void)in_sizes; (void)n_in; (void)out_size;
}

// Round 5
// 1222.450 us; speedup vs baseline: 3.9015x; 1.1039x over previous
//
#include <hip/hip_runtime.h>
#include <hip/hip_bf16.h>
#include <cstdint>
#include <cstddef>

// Cross_attention_dl: B=4, S=2048, D1=512, D2=1024. ALL I/O f32.
// Split-precision (bf16 hi/lo plane) MFMA pipeline; operands pre-split in
// global. K-loop: global_load_lds width-16 into [128][64] LDS tiles with
// XOR-swizzled column groups (group ^= row&7) to kill the 16-way ds_read_b128
// bank conflicts (round-4 counter: 3.8e7 conflict cycles/dispatch).

typedef __bf16 bf16;
typedef __attribute__((ext_vector_type(8))) __bf16 bf16x8;
typedef __attribute__((ext_vector_type(4))) __bf16 bf16x4;
typedef __attribute__((ext_vector_type(4))) float f32x4;

__device__ __forceinline__ void gld16(const bf16* g, bf16* s) {
    __builtin_amdgcn_global_load_lds(
        (const __attribute__((address_space(1))) void*)g,
        (__attribute__((address_space(3))) void*)s, 16, 0, 0);
}

// element offset of logical (row, col-group g) in a swizzled [128][64] tile
__device__ __forceinline__ int swz(int row, int g) {
    return row * 64 + ((g ^ (row & 7)) << 3);
}

// C = A @ B^T over bf16 planes. All strides in ELEMENTS.
// split=3: phases (A0,B0),(A1,B0),(A0,B1); split=1: (A0,B0) only.
// mode 0: f32 C[z][m][n] = acc (+resid*scale)
// mode 1: bf16 plane-pair row-major: C[p][z*M+m][n] = acc + bias[n] (+resid*scale)
// mode 2: bf16 plane-pair transposed: C[b][p][n][s] (b=grow>>11, s=grow&2047) = acc + bias[n]
__global__ __launch_bounds__(256) void gemm_split(
    const bf16* __restrict__ A, long lda, long psA, long bsA,
    const bf16* __restrict__ B, long ldb, long psB, long bsB,
    void* __restrict__ C, long ldc, long psC, long bsC, int mode,
    const float* __restrict__ bias,
    const float* __restrict__ resid, long ldr, long bsR,
    const float* __restrict__ scale,
    int K, int split)
{
    __shared__ __align__(16) bf16 As[128 * 64];
    __shared__ __align__(16) bf16 Bs[128 * 64];

    const int t    = threadIdx.x;
    const int wave = t >> 6;
    const int lane = t & 63;
    const int wr   = wave >> 1;
    const int wc   = wave & 1;
    const int r16  = lane & 15;
    const int quad = lane >> 4;

    const long row0 = (long)blockIdx.y * 128;
    const long col0 = (long)blockIdx.x * 128;
    const long z    = blockIdx.z;

    const int srow = (lane >> 3);                  // 0..7 within an 8-row chunk
    const int scol = ((lane & 7) ^ srow) * 8;      // swizzled col group this lane fetches

    f32x4 acc[4][4];
#pragma unroll
    for (int r = 0; r < 4; ++r)
#pragma unroll
        for (int c = 0; c < 4; ++c)
            acc[r][c] = (f32x4){0.f, 0.f, 0.f, 0.f};

    for (int ph = 0; ph < split; ++ph) {
        const bf16* Ab = A + z * bsA + (ph == 1 ? psA : 0);
        const bf16* Bb = B + z * bsB + (ph == 2 ? psB : 0);
        for (int kt = 0; kt < K; kt += 64) {
#pragma unroll
            for (int p = 0; p < 4; ++p) {
                const int chunk = wave * 32 + p * 8;   // 8 rows per 1KB wave store
                gld16(Ab + (row0 + chunk + srow) * lda + kt + scol, &As[chunk * 64]);
                gld16(Bb + (col0 + chunk + srow) * ldb + kt + scol, &Bs[chunk * 64]);
            }
            __syncthreads();
#pragma unroll
            for (int kk = 0; kk < 64; kk += 32) {
                const int g0 = (kk >> 3) + quad;
                bf16x8 af[4], bg[4];
#pragma unroll
                for (int r = 0; r < 4; ++r) {
                    int row = wr * 64 + r * 16 + r16;
                    af[r] = *reinterpret_cast<const bf16x8*>(&As[swz(row, g0)]);
                }
#pragma unroll
                for (int c = 0; c < 4; ++c) {
                    int row = wc * 64 + c * 16 + r16;
                    bg[c] = *reinterpret_cast<const bf16x8*>(&Bs[swz(row, g0)]);
                }
#pragma unroll
                for (int r = 0; r < 4; ++r)
#pragma unroll
                    for (int c = 0; c < 4; ++c)
                        acc[r][c] = __builtin_amdgcn_mfma_f32_16x16x32_bf16(af[r], bg[c], acc[r][c], 0, 0, 0);
            }
            __syncthreads();
        }
    }

    const float scv = resid ? *scale : 0.f;

#pragma unroll
    for (int r = 0; r < 4; ++r) {
#pragma unroll
        for (int c = 0; c < 4; ++c) {
            long gcol = col0 + wc * 64 + c * 16 + r16;
            float bv = bias ? bias[gcol] : 0.f;
#pragma unroll
            for (int i = 0; i < 4; ++i) {
                long grow = row0 + wr * 64 + r * 16 + quad * 4 + i;
                float val = acc[r][c][i] + bv;
                if (mode == 0) {
                    if (resid) val += resid[z * bsR + grow * ldr + gcol] * scv;
                    ((float*)C)[z * bsC + grow * ldc + gcol] = val;
                } else if (mode == 1) {
                    if (resid) val += resid[z * bsR + grow * ldr + gcol] * scv;
                    bf16* Cb = (bf16*)C + z * bsC;
                    bf16 h = (bf16)val;
                    Cb[grow * ldc + gcol] = h;
                    Cb[psC + grow * ldc + gcol] = (bf16)(val - (float)h);
                } else {
                    long b = grow >> 11, s = grow & 2047;
                    bf16* Cb = (bf16*)C + b * bsC;
                    bf16 h = (bf16)val;
                    Cb[gcol * ldc + s] = h;
                    Cb[psC + gcol * ldc + s] = (bf16)(val - (float)h);
                }
            }
        }
    }
}

// Row softmax over 2048 f32 cols; writes P IN PLACE as bf16 hi plane (cols
// [0,2048) of the row's 4096 bf16 slots) and lo plane (cols [2048,4096)).
__global__ __launch_bounds__(256) void softmax_planes(float* __restrict__ S)
{
    __shared__ float redm[4], reds[4];
    float* srow = S + (long)blockIdx.x * 2048;
    const int t = threadIdx.x;
    const int lane = t & 63;
    const int wave = t >> 6;

    f32x4 v0 = *reinterpret_cast<const f32x4*>(srow + t * 4);
    f32x4 v1 = *reinterpret_cast<const f32x4*>(srow + 1024 + t * 4);

    float m = v0[0];
#pragma unroll
    for (int i = 1; i < 4; ++i) m = fmaxf(m, v0[i]);
#pragma unroll
    for (int i = 0; i < 4; ++i) m = fmaxf(m, v1[i]);
#pragma unroll
    for (int off = 32; off > 0; off >>= 1) m = fmaxf(m, __shfl_xor(m, off));
    if (lane == 0) redm[wave] = m;
    __syncthreads();
    m = fmaxf(fmaxf(redm[0], redm[1]), fmaxf(redm[2], redm[3]));

    float s = 0.f;
#pragma unroll
    for (int i = 0; i < 4; ++i) { v0[i] = __expf(v0[i] - m); s += v0[i]; }
#pragma unroll
    for (int i = 0; i < 4; ++i) { v1[i] = __expf(v1[i] - m); s += v1[i]; }
#pragma unroll
    for (int off = 32; off > 0; off >>= 1) s += __shfl_xor(s, off);
    if (lane == 0) reds[wave] = s;
    __syncthreads();
    s = reds[0] + reds[1] + reds[2] + reds[3];
    float inv = 1.f / s;

    bf16x4 h0, h1, l0, l1;
#pragma unroll
    for (int i = 0; i < 4; ++i) {
        float a = v0[i] * inv, b = v1[i] * inv;
        h0[i] = (bf16)a; l0[i] = (bf16)(a - (float)h0[i]);
        h1[i] = (bf16)b; l1[i] = (bf16)(b - (float)h1[i]);
    }
    bf16* ph = (bf16*)srow;
    *reinterpret_cast<bf16x4*>(ph + t * 4) = h0;
    *reinterpret_cast<bf16x4*>(ph + 1024 + t * 4) = h1;
    *reinterpret_cast<bf16x4*>(ph + 2048 + t * 4) = l0;
    *reinterpret_cast<bf16x4*>(ph + 3072 + t * 4) = l1;
}

// f32[n] -> hi bf16[n], lo bf16[n] (lo plane at hi+n). n % 1024 == 0.
__global__ __launch_bounds__(256) void split_f32(
    const float* __restrict__ in, bf16* __restrict__ hi, long n)
{
    long i = ((long)blockIdx.x * 256 + threadIdx.x) * 4;
    f32x4 v = *reinterpret_cast<const f32x4*>(in + i);
    bf16x4 h, l;
#pragma unroll
    for (int j = 0; j < 4; ++j) {
        h[j] = (bf16)v[j];
        l[j] = (bf16)(v[j] - (float)h[j]);
    }
    *reinterpret_cast<bf16x4*>(hi + i) = h;
    *reinterpret_cast<bf16x4*>(hi + n + i) = l;
}

extern "C" void kernel_launch(void* const* d_in, const int* in_sizes, int n_in,
                              void* d_out, int out_size, void* d_ws, size_t ws_size,
                              hipStream_t stream)
{
    const float* x   = (const float*)d_in[0];
    const float* y   = (const float*)d_in[1];
    const float* Wq1 = (const float*)d_in[2];
    const float* bq1 = (const float*)d_in[3];
    const float* Wk1 = (const float*)d_in[4];
    const float* bk1 = (const float*)d_in[5];
    const float* Wv1 = (const float*)d_in[6];
    const float* bv1 = (const float*)d_in[7];
    const float* Wq2 = (const float*)d_in[8];
    const float* bq2 = (const float*)d_in[9];
    const float* Wk2 = (const float*)d_in[10];
    const float* bk2 = (const float*)d_in[11];
    const float* Wv2 = (const float*)d_in[12];
    const float* bv2 = (const float*)d_in[13];
    const float* w1  = (const float*)d_in[14];
    const float* w2  = (const float*)d_in[15];
    float* out = (float*)d_out;

    const size_t MB = 1ull << 20;
    char* ws = (char*)d_ws;
    const long S = 2048, M4 = 8192, E1 = 512, E2 = 1024;
    const long W1ps = E1 * E1, W2ps = E2 * E2;

    // cfg 2 (ws >= 207MB): z=4-batched scores/softmax/PV, batched projections.
    // cfg 0 (75MB): per-batch pipeline; W2 planes staged in d_out after stage 1.
    const int cfg = (ws_size >= 207 * MB) ? 2 : 0;

    bf16 *Wq1p, *Wk1p, *Wv1p, *Wq2p, *Wk2p, *Wv2p, *temp, *qb, *kb, *vt;
    float* Sc;
    bf16* xp = (bf16*)d_out;             // [2][8192][512] planes (16MB), dead after stage-1 proj
    bf16* yp = xp + 2 * M4 * E1;         // next 16MB of d_out
    if (cfg == 2) {
        Wq1p = (bf16*)(ws + 0 * MB);  Wk1p = (bf16*)(ws + 1 * MB);  Wv1p = (bf16*)(ws + 2 * MB);
        Wq2p = (bf16*)(ws + 3 * MB);  Wk2p = (bf16*)(ws + 7 * MB);  Wv2p = (bf16*)(ws + 11 * MB);
        temp = (bf16*)(ws + 15 * MB);                 // [2][8192][1024] 32MB
        qb   = (bf16*)(ws + 47 * MB);                 // [2][8192][E]   32MB
        kb   = (bf16*)(ws + 79 * MB);
        vt   = (bf16*)(ws + 111 * MB);                // [4][2][E][2048] 32MB
        Sc   = (float*)(ws + 143 * MB);               // [4][2048][2048] 64MB
    } else {
        Wq1p = (bf16*)(ws + 0 * MB);  Wk1p = (bf16*)(ws + 1 * MB);  Wv1p = (bf16*)(ws + 2 * MB);
        temp = (bf16*)(ws + 3 * MB);                  // 32MB
        qb   = (bf16*)(ws + 35 * MB);                 // [2][2048][E] 8MB
        kb   = (bf16*)(ws + 43 * MB);
        vt   = (bf16*)(ws + 51 * MB);                 // [2][E][2048] 8MB
        Sc   = (float*)(ws + 59 * MB);                // [2048][2048] 16MB
        Wq2p = (bf16*)d_out;                          // staged after stage 1 (xp dead)
        Wk2p = Wq2p + 2 * W2ps;
        Wv2p = Wk2p + 2 * W2ps;
    }

    auto gemm = [&](const bf16* A, long lda, long psA, long bsA,
                    const bf16* B, long ldb, long psB, long bsB,
                    void* C, long ldc, long psC, long bsC, int mode,
                    const float* bias, const float* resid, long ldr, long bsR,
                    const float* scale, int M, int N, int K, int split, int gz) {
        gemm_split<<<dim3(N / 128, M / 128, gz), dim3(256), 0, stream>>>(
            A, lda, psA, bsA, B, ldb, psB, bsB, C, ldc, psC, bsC, mode,
            bias, resid, ldr, bsR, scale, K, split);
    };
    auto conv = [&](const float* in, bf16* planes, long n) {
        split_f32<<<dim3((unsigned)(n / 1024)), dim3(256), 0, stream>>>(in, planes, n);
    };

    conv(x, xp, M4 * E1);
    conv(y, yp, M4 * E1);
    conv(Wq1, Wq1p, W1ps); conv(Wk1, Wk1p, W1ps); conv(Wv1, Wv1p, W1ps);
    if (cfg == 2) { conv(Wq2, Wq2p, W2ps); conv(Wk2, Wk2p, W2ps); conv(Wv2, Wv2p, W2ps); }

    // stage-1 attention (D=E=512) for one path; writes temp[:, colOff:colOff+512]
    auto stage1 = [&](const bf16* sp, const float* resid, const float* scale, long colOff) {
        if (cfg == 2) {
            gemm(sp, E1, M4 * E1, 0, Wq1p, E1, W1ps, 0, qb, E1, M4 * E1, 0, 1,
                 bq1, nullptr, 0, 0, nullptr, 8192, 512, 512, 3, 1);
            gemm(sp, E1, M4 * E1, 0, Wk1p, E1, W1ps, 0, kb, E1, M4 * E1, 0, 1,
                 bk1, nullptr, 0, 0, nullptr, 8192, 512, 512, 3, 1);
            gemm(sp, E1, M4 * E1, 0, Wv1p, E1, W1ps, 0, vt, S, E1 * S, 2 * E1 * S, 2,
                 bv1, nullptr, 0, 0, nullptr, 8192, 512, 512, 3, 1);
            gemm(qb, E1, M4 * E1, S * E1, kb, E1, M4 * E1, S * E1, Sc, S, 0, S * S, 0,
                 nullptr, nullptr, 0, 0, nullptr, 2048, 2048, 512, 3, 4);
            softmax_planes<<<dim3(8192), dim3(256), 0, stream>>>(Sc);
            gemm((const bf16*)Sc, 4096, 2048, S * 4096, vt, S, E1 * S, 2 * E1 * S,
                 temp + colOff, 1024, M4 * 1024, S * 1024, 1,
                 nullptr, resid, E1, S * E1, scale, 2048, 512, 2048, 3, 4);
        } else {
            for (int b = 0; b < 4; ++b) {
                const bf16* sb = sp + (long)b * S * E1;
                gemm(sb, E1, M4 * E1, 0, Wq1p, E1, W1ps, 0, qb, E1, S * E1, 0, 1,
                     bq1, nullptr, 0, 0, nullptr, 2048, 512, 512, 3, 1);
                gemm(sb, E1, M4 * E1, 0, Wk1p, E1, W1ps, 0, kb, E1, S * E1, 0, 1,
                     bk1, nullptr, 0, 0, nullptr, 2048, 512, 512, 3, 1);
                gemm(sb, E1, M4 * E1, 0, Wv1p, E1, W1ps, 0, vt, S, E1 * S, 0, 2,
                     bv1, nullptr, 0, 0, nullptr, 2048, 512, 512, 3, 1);
                gemm(qb, E1, S * E1, 0, kb, E1, S * E1, 0, Sc, S, 0, 0, 0,
                     nullptr, nullptr, 0, 0, nullptr, 2048, 2048, 512, 3, 1);
                softmax_planes<<<dim3(2048), dim3(256), 0, stream>>>(Sc);
                gemm((const bf16*)Sc, 4096, 2048, 0, vt, S, E1 * S, 0,
                     temp + colOff + (long)b * S * 1024, 1024, M4 * 1024, 0, 1,
                     nullptr, resid + (long)b * S * E1, E1, 0, scale, 2048, 512, 2048, 3, 1);
            }
        }
    };

    stage1(xp, y, w2, 0);     // x1 = attn(x) + y*weight2
    stage1(yp, x, w1, 512);   // y1 = attn(y) + x*weight1

    if (cfg == 0) { conv(Wq2, Wq2p, W2ps); conv(Wk2, Wk2p, W2ps); conv(Wv2, Wv2p, W2ps); }

    // stage-2 attention over temp (D=E=1024) -> out
    if (cfg == 2) {
        gemm(temp, E2, M4 * E2, 0, Wq2p, E2, W2ps, 0, qb, E2, M4 * E2, 0, 1,
             bq2, nullptr, 0, 0, nullptr, 8192, 1024, 1024, 3, 1);
        gemm(temp, E2, M4 * E2, 0, Wk2p, E2, W2ps, 0, kb, E2, M4 * E2, 0, 1,
             bk2, nullptr, 0, 0, nullptr, 8192, 1024, 1024, 3, 1);
        gemm(temp, E2, M4 * E2, 0, Wv2p, E2, W2ps, 0, vt, S, E2 * S, 2 * E2 * S, 2,
             bv2, nullptr, 0, 0, nullptr, 8192, 1024, 1024, 1, 1);
        gemm(qb, E2, M4 * E2, S * E2, kb, E2, M4 * E2, S * E2, Sc, S, 0, S * S, 0,
             nullptr, nullptr, 0, 0, nullptr, 2048, 2048, 1024, 3, 4);
        softmax_planes<<<dim3(8192), dim3(256), 0, stream>>>(Sc);
        gemm((const bf16*)Sc, 4096, 2048, S * 4096, vt, S, E2 * S, 2 * E2 * S,
             out, E2, 0, S * E2, 0, nullptr, nullptr, 0, 0, nullptr,
             2048, 1024, 2048, 1, 4);
    } else {
        for (int b = 0; b < 4; ++b) {
            const bf16* tb = temp + (long)b * S * E2;
            gemm(tb, E2, M4 * E2, 0, Wq2p, E2, W2ps, 0, qb, E2, S * E2, 0, 1,
                 bq2, nullptr, 0, 0, nullptr, 2048, 1024, 1024, 3, 1);
            gemm(tb, E2, M4 * E2, 0, Wk2p, E2, W2ps, 0, kb, E2, S * E2, 0, 1,
                 bk2, nullptr, 0, 0, nullptr, 2048, 1024, 1024, 3, 1);
            gemm(tb, E2, M4 * E2, 0, Wv2p, E2, W2ps, 0, vt, S, E2 * S, 0, 2,
                 bv2, nullptr, 0, 0, nullptr, 2048, 1024, 1024, 1, 1);
            gemm(qb, E2, S * E2, 0, kb, E2, S * E2, 0, Sc, S, 0, 0, 0,
                 nullptr, nullptr, 0, 0, nullptr, 2048, 2048, 1024, 3, 1);
            softmax_planes<<<dim3(2048), dim3(256), 0, stream>>>(Sc);
            gemm((const bf16*)Sc, 4096, 2048, 0, vt, S, E2 * S, 0,
                 out + (long)b * S * E2, E2, 0, 0, 0, nullptr, nullptr, 0, 0, nullptr,
                 2048, 1024, 2048, 1, 1);
        }
    }

    (void)in_sizes; (void)n_in; (void)out_size;
}

// Round 6
// 1121.148 us; speedup vs baseline: 4.2540x; 1.0904x over previous
//
#include <hip/hip_runtime.h>
#include <hip/hip_bf16.h>
#include <cstdint>
#include <cstddef>

// Cross_attention_dl: B=4, S=2048, D1=512, D2=1024. ALL I/O f32.
// Split-precision (bf16 hi/lo plane) MFMA pipeline; operands pre-split in
// global. Round 6: (a) XCD-aware flat-grid swizzle so x-mates share an XCD's
// L2 (cuts PV re-fetch), (b) double-buffered K-loop with raw s_barrier +
// explicit s_waitcnt vmcnt(8) for the 1-block/CU dispatches (proj, PV).

typedef __bf16 bf16;
typedef __attribute__((ext_vector_type(8))) __bf16 bf16x8;
typedef __attribute__((ext_vector_type(4))) __bf16 bf16x4;
typedef __attribute__((ext_vector_type(4))) float f32x4;

__device__ __forceinline__ void gld16(const bf16* g, bf16* s) {
    __builtin_amdgcn_global_load_lds(
        (const __attribute__((address_space(1))) void*)g,
        (__attribute__((address_space(3))) void*)s, 16, 0, 0);
}

// gfx9 waitcnt imm: vmcnt[3:0]+[15:14], expcnt[6:4], lgkmcnt[11:8]
#define WAIT_VM8   __builtin_amdgcn_s_waitcnt(8 | (7 << 4) | (0xF << 8))
#define WAIT_VM0   __builtin_amdgcn_s_waitcnt(0 | (7 << 4) | (0xF << 8))
#define WAIT_LGKM0 __builtin_amdgcn_s_waitcnt(0xF | (7 << 4) | (0 << 8) | (3 << 14))

// element offset of logical (row, col-group g) in a swizzled [128][64] tile
__device__ __forceinline__ int swz(int row, int g) {
    return row * 64 + ((g ^ (row & 7)) << 3);
}

// C = A @ B^T over bf16 planes. All strides in ELEMENTS. Flat 1-D grid;
// decode gives x-mates (same y,z) indices 8 apart => same XCD (round-robin).
// split=3: phases (A0,B0),(A1,B0),(A0,B1); split=1: (A0,B0) only.
// mode 0: f32 C[z][m][n] = acc (+resid*scale)
// mode 1: bf16 plane-pair row-major: C[p][z*M+m][n] = acc + bias[n] (+resid*scale)
// mode 2: bf16 plane-pair transposed: C[b][p][n][s] (b=grow>>11, s=grow&2047)
template <bool DBUF>
__global__ __launch_bounds__(256) void gemm_split(
    const bf16* __restrict__ A, long lda, long psA, long bsA,
    const bf16* __restrict__ B, long ldb, long psB, long bsB,
    void* __restrict__ C, long ldc, long psC, long bsC, int mode,
    const float* __restrict__ bias,
    const float* __restrict__ resid, long ldr, long bsR,
    const float* __restrict__ scale,
    int K, int split, int nx, int ny)
{
    __shared__ __align__(16) bf16 As[DBUF ? 2 : 1][128 * 64];
    __shared__ __align__(16) bf16 Bs[DBUF ? 2 : 1][128 * 64];

    const int t    = threadIdx.x;
    const int wave = t >> 6;
    const int lane = t & 63;
    const int wr   = wave >> 1;
    const int wc   = wave & 1;
    const int r16  = lane & 15;
    const int quad = lane >> 4;

    // flat-grid decode: g = low(3b) + 8*(x + nx*hi); yz = low + 8*hi
    const int g  = blockIdx.x;
    const int xb = (g >> 3) % nx;
    const int hi = (g >> 3) / nx;
    const int yz = (g & 7) + 8 * hi;
    const int yb = yz % ny;
    const long z = yz / ny;

    const long row0 = (long)yb * 128;
    const long col0 = (long)xb * 128;

    const int srow = (lane >> 3);                  // 0..7 within an 8-row chunk
    const int scol = ((lane & 7) ^ srow) * 8;      // swizzled col group this lane fetches

    const int ktiles = K >> 6;
    const int T = split * ktiles;

    const bf16* Az = A + z * bsA;
    const bf16* Bz = B + z * bsB;

    auto prefetch = [&](int ti, int buf) {
        const int ph = ti / ktiles;
        const int kt = (ti - ph * ktiles) << 6;
        const bf16* Ab = Az + (ph == 1 ? psA : 0);
        const bf16* Bb = Bz + (ph == 2 ? psB : 0);
#pragma unroll
        for (int p = 0; p < 4; ++p) {
            const int chunk = wave * 32 + p * 8;   // 8 rows per 1KB wave store
            gld16(Ab + (row0 + chunk + srow) * lda + kt + scol, &As[buf][chunk * 64]);
            gld16(Bb + (col0 + chunk + srow) * ldb + kt + scol, &Bs[buf][chunk * 64]);
        }
    };

    f32x4 acc[4][4];
#pragma unroll
    for (int r = 0; r < 4; ++r)
#pragma unroll
        for (int c = 0; c < 4; ++c)
            acc[r][c] = (f32x4){0.f, 0.f, 0.f, 0.f};

    if constexpr (DBUF) {
        prefetch(0, 0);
        prefetch(1, 1);
        for (int ti = 0; ti < T; ++ti) {
            const int cur = ti & 1;
            if (ti + 1 < T) WAIT_VM8; else WAIT_VM0;   // oldest 8 (cur tile) landed
            __builtin_amdgcn_s_barrier();
            bf16x8 af[2][4], bg[2][4];
#pragma unroll
            for (int kk = 0; kk < 2; ++kk) {
                const int g0 = (kk << 2) + quad;
#pragma unroll
                for (int r = 0; r < 4; ++r)
                    af[kk][r] = *reinterpret_cast<const bf16x8*>(&As[cur][swz(wr * 64 + r * 16 + r16, g0)]);
#pragma unroll
                for (int c = 0; c < 4; ++c)
                    bg[kk][c] = *reinterpret_cast<const bf16x8*>(&Bs[cur][swz(wc * 64 + c * 16 + r16, g0)]);
            }
            WAIT_LGKM0;                                 // frags in regs
            __builtin_amdgcn_s_barrier();               // cur buffer free
            if (ti + 2 < T) prefetch(ti + 2, cur);
#pragma unroll
            for (int kk = 0; kk < 2; ++kk)
#pragma unroll
                for (int r = 0; r < 4; ++r)
#pragma unroll
                    for (int c = 0; c < 4; ++c)
                        acc[r][c] = __builtin_amdgcn_mfma_f32_16x16x32_bf16(af[kk][r], bg[kk][c], acc[r][c], 0, 0, 0);
        }
    } else {
        for (int ti = 0; ti < T; ++ti) {
            prefetch(ti, 0);
            __syncthreads();
#pragma unroll
            for (int kk = 0; kk < 2; ++kk) {
                const int g0 = (kk << 2) + quad;
                bf16x8 af[4], bg[4];
#pragma unroll
                for (int r = 0; r < 4; ++r)
                    af[r] = *reinterpret_cast<const bf16x8*>(&As[0][swz(wr * 64 + r * 16 + r16, g0)]);
#pragma unroll
                for (int c = 0; c < 4; ++c)
                    bg[c] = *reinterpret_cast<const bf16x8*>(&Bs[0][swz(wc * 64 + c * 16 + r16, g0)]);
#pragma unroll
                for (int r = 0; r < 4; ++r)
#pragma unroll
                    for (int c = 0; c < 4; ++c)
                        acc[r][c] = __builtin_amdgcn_mfma_f32_16x16x32_bf16(af[r], bg[c], acc[r][c], 0, 0, 0);
            }
            __syncthreads();
        }
    }

    const float scv = resid ? *scale : 0.f;

#pragma unroll
    for (int r = 0; r < 4; ++r) {
#pragma unroll
        for (int c = 0; c < 4; ++c) {
            long gcol = col0 + wc * 64 + c * 16 + r16;
            float bv = bias ? bias[gcol] : 0.f;
#pragma unroll
            for (int i = 0; i < 4; ++i) {
                long grow = row0 + wr * 64 + r * 16 + quad * 4 + i;
                float val = acc[r][c][i] + bv;
                if (mode == 0) {
                    if (resid) val += resid[z * bsR + grow * ldr + gcol] * scv;
                    ((float*)C)[z * bsC + grow * ldc + gcol] = val;
                } else if (mode == 1) {
                    if (resid) val += resid[z * bsR + grow * ldr + gcol] * scv;
                    bf16* Cb = (bf16*)C + z * bsC;
                    bf16 h = (bf16)val;
                    Cb[grow * ldc + gcol] = h;
                    Cb[psC + grow * ldc + gcol] = (bf16)(val - (float)h);
                } else {
                    long b = grow >> 11, s = grow & 2047;
                    bf16* Cb = (bf16*)C + b * bsC;
                    bf16 h = (bf16)val;
                    Cb[gcol * ldc + s] = h;
                    Cb[psC + gcol * ldc + s] = (bf16)(val - (float)h);
                }
            }
        }
    }
}

// Row softmax over 2048 f32 cols; writes P IN PLACE as bf16 hi plane (cols
// [0,2048) of the row's 4096 bf16 slots) and lo plane (cols [2048,4096)).
__global__ __launch_bounds__(256) void softmax_planes(float* __restrict__ S)
{
    __shared__ float redm[4], reds[4];
    float* srow = S + (long)blockIdx.x * 2048;
    const int t = threadIdx.x;
    const int lane = t & 63;
    const int wave = t >> 6;

    f32x4 v0 = *reinterpret_cast<const f32x4*>(srow + t * 4);
    f32x4 v1 = *reinterpret_cast<const f32x4*>(srow + 1024 + t * 4);

    float m = v0[0];
#pragma unroll
    for (int i = 1; i < 4; ++i) m = fmaxf(m, v0[i]);
#pragma unroll
    for (int i = 0; i < 4; ++i) m = fmaxf(m, v1[i]);
#pragma unroll
    for (int off = 32; off > 0; off >>= 1) m = fmaxf(m, __shfl_xor(m, off));
    if (lane == 0) redm[wave] = m;
    __syncthreads();
    m = fmaxf(fmaxf(redm[0], redm[1]), fmaxf(redm[2], redm[3]));

    float s = 0.f;
#pragma unroll
    for (int i = 0; i < 4; ++i) { v0[i] = __expf(v0[i] - m); s += v0[i]; }
#pragma unroll
    for (int i = 0; i < 4; ++i) { v1[i] = __expf(v1[i] - m); s += v1[i]; }
#pragma unroll
    for (int off = 32; off > 0; off >>= 1) s += __shfl_xor(s, off);
    if (lane == 0) reds[wave] = s;
    __syncthreads();
    s = reds[0] + reds[1] + reds[2] + reds[3];
    float inv = 1.f / s;

    bf16x4 h0, h1, l0, l1;
#pragma unroll
    for (int i = 0; i < 4; ++i) {
        float a = v0[i] * inv, b = v1[i] * inv;
        h0[i] = (bf16)a; l0[i] = (bf16)(a - (float)h0[i]);
        h1[i] = (bf16)b; l1[i] = (bf16)(b - (float)h1[i]);
    }
    bf16* ph = (bf16*)srow;
    *reinterpret_cast<bf16x4*>(ph + t * 4) = h0;
    *reinterpret_cast<bf16x4*>(ph + 1024 + t * 4) = h1;
    *reinterpret_cast<bf16x4*>(ph + 2048 + t * 4) = l0;
    *reinterpret_cast<bf16x4*>(ph + 3072 + t * 4) = l1;
}

// f32[n] -> hi bf16[n], lo bf16[n] (lo plane at hi+n). n % 1024 == 0.
__global__ __launch_bounds__(256) void split_f32(
    const float* __restrict__ in, bf16* __restrict__ hi, long n)
{
    long i = ((long)blockIdx.x * 256 + threadIdx.x) * 4;
    f32x4 v = *reinterpret_cast<const f32x4*>(in + i);
    bf16x4 h, l;
#pragma unroll
    for (int j = 0; j < 4; ++j) {
        h[j] = (bf16)v[j];
        l[j] = (bf16)(v[j] - (float)h[j]);
    }
    *reinterpret_cast<bf16x4*>(hi + i) = h;
    *reinterpret_cast<bf16x4*>(hi + n + i) = l;
}

extern "C" void kernel_launch(void* const* d_in, const int* in_sizes, int n_in,
                              void* d_out, int out_size, void* d_ws, size_t ws_size,
                              hipStream_t stream)
{
    const float* x   = (const float*)d_in[0];
    const float* y   = (const float*)d_in[1];
    const float* Wq1 = (const float*)d_in[2];
    const float* bq1 = (const float*)d_in[3];
    const float* Wk1 = (const float*)d_in[4];
    const float* bk1 = (const float*)d_in[5];
    const float* Wv1 = (const float*)d_in[6];
    const float* bv1 = (const float*)d_in[7];
    const float* Wq2 = (const float*)d_in[8];
    const float* bq2 = (const float*)d_in[9];
    const float* Wk2 = (const float*)d_in[10];
    const float* bk2 = (const float*)d_in[11];
    const float* Wv2 = (const float*)d_in[12];
    const float* bv2 = (const float*)d_in[13];
    const float* w1  = (const float*)d_in[14];
    const float* w2  = (const float*)d_in[15];
    float* out = (float*)d_out;

    const size_t MB = 1ull << 20;
    char* ws = (char*)d_ws;
    const long S = 2048, M4 = 8192, E1 = 512, E2 = 1024;
    const long W1ps = E1 * E1, W2ps = E2 * E2;

    const int cfg = (ws_size >= 207 * MB) ? 2 : 0;

    bf16 *Wq1p, *Wk1p, *Wv1p, *Wq2p, *Wk2p, *Wv2p, *temp, *qb, *kb, *vt;
    float* Sc;
    bf16* xp = (bf16*)d_out;             // [2][8192][512] planes (16MB), dead after stage-1 proj
    bf16* yp = xp + 2 * M4 * E1;
    if (cfg == 2) {
        Wq1p = (bf16*)(ws + 0 * MB);  Wk1p = (bf16*)(ws + 1 * MB);  Wv1p = (bf16*)(ws + 2 * MB);
        Wq2p = (bf16*)(ws + 3 * MB);  Wk2p = (bf16*)(ws + 7 * MB);  Wv2p = (bf16*)(ws + 11 * MB);
        temp = (bf16*)(ws + 15 * MB);                 // [2][8192][1024] 32MB
        qb   = (bf16*)(ws + 47 * MB);                 // [2][8192][E]   32MB
        kb   = (bf16*)(ws + 79 * MB);
        vt   = (bf16*)(ws + 111 * MB);                // [4][2][E][2048] 32MB
        Sc   = (float*)(ws + 143 * MB);               // [4][2048][2048] 64MB
    } else {
        Wq1p = (bf16*)(ws + 0 * MB);  Wk1p = (bf16*)(ws + 1 * MB);  Wv1p = (bf16*)(ws + 2 * MB);
        temp = (bf16*)(ws + 3 * MB);
        qb   = (bf16*)(ws + 35 * MB);
        kb   = (bf16*)(ws + 43 * MB);
        vt   = (bf16*)(ws + 51 * MB);
        Sc   = (float*)(ws + 59 * MB);
        Wq2p = (bf16*)d_out;
        Wk2p = Wq2p + 2 * W2ps;
        Wv2p = Wk2p + 2 * W2ps;
    }

    // db=true -> double-buffered kernel (for 1-block/CU dispatches: proj, PV)
    auto gemm = [&](const bf16* A, long lda, long psA, long bsA,
                    const bf16* B, long ldb, long psB, long bsB,
                    void* C, long ldc, long psC, long bsC, int mode,
                    const float* bias, const float* resid, long ldr, long bsR,
                    const float* scale, int M, int N, int K, int split, int gz,
                    bool db) {
        int nx = N / 128, ny = M / 128;
        dim3 g((unsigned)(nx * ny * gz));
        if (db)
            gemm_split<true><<<g, dim3(256), 0, stream>>>(
                A, lda, psA, bsA, B, ldb, psB, bsB, C, ldc, psC, bsC, mode,
                bias, resid, ldr, bsR, scale, K, split, nx, ny);
        else
            gemm_split<false><<<g, dim3(256), 0, stream>>>(
                A, lda, psA, bsA, B, ldb, psB, bsB, C, ldc, psC, bsC, mode,
                bias, resid, ldr, bsR, scale, K, split, nx, ny);
    };
    auto conv = [&](const float* in, bf16* planes, long n) {
        split_f32<<<dim3((unsigned)(n / 1024)), dim3(256), 0, stream>>>(in, planes, n);
    };

    conv(x, xp, M4 * E1);
    conv(y, yp, M4 * E1);
    conv(Wq1, Wq1p, W1ps); conv(Wk1, Wk1p, W1ps); conv(Wv1, Wv1p, W1ps);
    if (cfg == 2) { conv(Wq2, Wq2p, W2ps); conv(Wk2, Wk2p, W2ps); conv(Wv2, Wv2p, W2ps); }

    auto stage1 = [&](const bf16* sp, const float* resid, const float* scale, long colOff) {
        if (cfg == 2) {
            gemm(sp, E1, M4 * E1, 0, Wq1p, E1, W1ps, 0, qb, E1, M4 * E1, 0, 1,
                 bq1, nullptr, 0, 0, nullptr, 8192, 512, 512, 3, 1, true);
            gemm(sp, E1, M4 * E1, 0, Wk1p, E1, W1ps, 0, kb, E1, M4 * E1, 0, 1,
                 bk1, nullptr, 0, 0, nullptr, 8192, 512, 512, 3, 1, true);
            gemm(sp, E1, M4 * E1, 0, Wv1p, E1, W1ps, 0, vt, S, E1 * S, 2 * E1 * S, 2,
                 bv1, nullptr, 0, 0, nullptr, 8192, 512, 512, 3, 1, true);
            gemm(qb, E1, M4 * E1, S * E1, kb, E1, M4 * E1, S * E1, Sc, S, 0, S * S, 0,
                 nullptr, nullptr, 0, 0, nullptr, 2048, 2048, 512, 3, 4, false);
            softmax_planes<<<dim3(8192), dim3(256), 0, stream>>>(Sc);
            gemm((const bf16*)Sc, 4096, 2048, S * 4096, vt, S, E1 * S, 2 * E1 * S,
                 temp + colOff, 1024, M4 * 1024, S * 1024, 1,
                 nullptr, resid, E1, S * E1, scale, 2048, 512, 2048, 3, 4, true);
        } else {
            for (int b = 0; b < 4; ++b) {
                const bf16* sb = sp + (long)b * S * E1;
                gemm(sb, E1, M4 * E1, 0, Wq1p, E1, W1ps, 0, qb, E1, S * E1, 0, 1,
                     bq1, nullptr, 0, 0, nullptr, 2048, 512, 512, 3, 1, true);
                gemm(sb, E1, M4 * E1, 0, Wk1p, E1, W1ps, 0, kb, E1, S * E1, 0, 1,
                     bk1, nullptr, 0, 0, nullptr, 2048, 512, 512, 3, 1, true);
                gemm(sb, E1, M4 * E1, 0, Wv1p, E1, W1ps, 0, vt, S, E1 * S, 0, 2,
                     bv1, nullptr, 0, 0, nullptr, 2048, 512, 512, 3, 1, true);
                gemm(qb, E1, S * E1, 0, kb, E1, S * E1, 0, Sc, S, 0, 0, 0,
                     nullptr, nullptr, 0, 0, nullptr, 2048, 2048, 512, 3, 1, false);
                softmax_planes<<<dim3(2048), dim3(256), 0, stream>>>(Sc);
                gemm((const bf16*)Sc, 4096, 2048, 0, vt, S, E1 * S, 0,
                     temp + colOff + (long)b * S * 1024, 1024, M4 * 1024, 0, 1,
                     nullptr, resid + (long)b * S * E1, E1, 0, scale, 2048, 512, 2048, 3, 1, true);
            }
        }
    };

    stage1(xp, y, w2, 0);     // x1 = attn(x) + y*weight2
    stage1(yp, x, w1, 512);   // y1 = attn(y) + x*weight1

    if (cfg == 0) { conv(Wq2, Wq2p, W2ps); conv(Wk2, Wk2p, W2ps); conv(Wv2, Wv2p, W2ps); }

    if (cfg == 2) {
        gemm(temp, E2, M4 * E2, 0, Wq2p, E2, W2ps, 0, qb, E2, M4 * E2, 0, 1,
             bq2, nullptr, 0, 0, nullptr, 8192, 1024, 1024, 3, 1, true);
        gemm(temp, E2, M4 * E2, 0, Wk2p, E2, W2ps, 0, kb, E2, M4 * E2, 0, 1,
             bk2, nullptr, 0, 0, nullptr, 8192, 1024, 1024, 3, 1, true);
        gemm(temp, E2, M4 * E2, 0, Wv2p, E2, W2ps, 0, vt, S, E2 * S, 2 * E2 * S, 2,
             bv2, nullptr, 0, 0, nullptr, 8192, 1024, 1024, 1, 1, true);
        gemm(qb, E2, M4 * E2, S * E2, kb, E2, M4 * E2, S * E2, Sc, S, 0, S * S, 0,
             nullptr, nullptr, 0, 0, nullptr, 2048, 2048, 1024, 3, 4, false);
        softmax_planes<<<dim3(8192), dim3(256), 0, stream>>>(Sc);
        gemm((const bf16*)Sc, 4096, 2048, S * 4096, vt, S, E2 * S, 2 * E2 * S,
             out, E2, 0, S * E2, 0, nullptr, nullptr, 0, 0, nullptr,
             2048, 1024, 2048, 1, 4, true);
    } else {
        for (int b = 0; b < 4; ++b) {
            const bf16* tb = temp + (long)b * S * E2;
            gemm(tb, E2, M4 * E2, 0, Wq2p, E2, W2ps, 0, qb, E2, S * E2, 0, 1,
                 bq2, nullptr, 0, 0, nullptr, 2048, 1024, 1024, 3, 1, true);
            gemm(tb, E2, M4 * E2, 0, Wk2p, E2, W2ps, 0, kb, E2, S * E2, 0, 1,
                 bk2, nullptr, 0, 0, nullptr, 2048, 1024, 1024, 3, 1, true);
            gemm(tb, E2, M4 * E2, 0, Wv2p, E2, W2ps, 0, vt, S, E2 * S, 0, 2,
                 bv2, nullptr, 0, 0, nullptr, 2048, 1024, 1024, 1, 1, true);
            gemm(qb, E2, S * E2, 0, kb, E2, S * E2, 0, Sc, S, 0, 0, 0,
                 nullptr, nullptr, 0, 0, nullptr, 2048, 2048, 1024, 3, 1, false);
            softmax_planes<<<dim3(2048), dim3(256), 0, stream>>>(Sc);
            gemm((const bf16*)Sc, 4096, 2048, 0, vt, S, E2 * S, 0,
                 out + (long)b * S * E2, E2, 0, 0, 0, nullptr, nullptr, 0, 0, nullptr,
                 2048, 1024, 2048, 1, 1, true);
        }
    }

    (void)in_sizes; (void)n_in; (void)out_size;
}

// Round 7
// 1099.866 us; speedup vs baseline: 4.3363x; 1.0193x over previous
//
#include <hip/hip_runtime.h>
#include <hip/hip_bf16.h>
#include <cstdint>
#include <cstddef>

// Cross_attention_dl: B=4, S=2048, D1=512, D2=1024. ALL I/O f32.
// Split-precision (bf16 hi/lo plane) MFMA pipeline; operands pre-split in
// global. Round 7: XCD super-tile grid decode — each XCD (round-robin g%8)
// owns whole 4x4 (y,x) block super-tiles so both A- and B-strips are reused
// within one XCD's L2 (round-6 counter: score-s1 FETCH 221 MB ~= whole K
// operand per XCD; dispatch was HBM-traffic-bound at 160 us).

typedef __bf16 bf16;
typedef __attribute__((ext_vector_type(8))) __bf16 bf16x8;
typedef __attribute__((ext_vector_type(4))) __bf16 bf16x4;
typedef __attribute__((ext_vector_type(4))) float f32x4;

__device__ __forceinline__ void gld16(const bf16* g, bf16* s) {
    __builtin_amdgcn_global_load_lds(
        (const __attribute__((address_space(1))) void*)g,
        (__attribute__((address_space(3))) void*)s, 16, 0, 0);
}

// gfx9 waitcnt imm: vmcnt[3:0]+[15:14], expcnt[6:4], lgkmcnt[11:8]
#define WAIT_VM8   __builtin_amdgcn_s_waitcnt(8 | (7 << 4) | (0xF << 8))
#define WAIT_VM0   __builtin_amdgcn_s_waitcnt(0 | (7 << 4) | (0xF << 8))
#define WAIT_LGKM0 __builtin_amdgcn_s_waitcnt(0xF | (7 << 4) | (0 << 8) | (3 << 14))

// element offset of logical (row, col-group g) in a swizzled [128][64] tile
__device__ __forceinline__ int swz(int row, int g) {
    return row * 64 + ((g ^ (row & 7)) << 3);
}

// C = A @ B^T over bf16 planes. All strides in ELEMENTS. Flat 1-D grid with
// XCD super-tile decode: xcd = g&7 owns 4x4 (y,x) super-tiles, 16 consecutive
// per-XCD blocks = one super-tile (requires grid % 128 == 0).
// split=3: phases (A0,B0),(A1,B0),(A0,B1); split=1: (A0,B0) only.
// mode 0: f32 C[z][m][n] = acc (+resid*scale)
// mode 1: bf16 plane-pair row-major: C[p][z*M+m][n] = acc + bias[n] (+resid*scale)
// mode 2: bf16 plane-pair transposed: C[b][p][n][s] (b=grow>>11, s=grow&2047)
template <bool DBUF>
__global__ __launch_bounds__(256) void gemm_split(
    const bf16* __restrict__ A, long lda, long psA, long bsA,
    const bf16* __restrict__ B, long ldb, long psB, long bsB,
    void* __restrict__ C, long ldc, long psC, long bsC, int mode,
    const float* __restrict__ bias,
    const float* __restrict__ resid, long ldr, long bsR,
    const float* __restrict__ scale,
    int K, int split, int nx, int ny)
{
    __shared__ __align__(16) bf16 As[DBUF ? 2 : 1][128 * 64];
    __shared__ __align__(16) bf16 Bs[DBUF ? 2 : 1][128 * 64];

    const int t    = threadIdx.x;
    const int wave = t >> 6;
    const int lane = t & 63;
    const int wr   = wave >> 1;
    const int wc   = wave & 1;
    const int r16  = lane & 15;
    const int quad = lane >> 4;

    // XCD super-tile decode
    {
    }
    const int g   = blockIdx.x;
    const int tk  = g >> 3;                       // per-XCD block counter
    const int S   = (g & 7) + 8 * (tk >> 4);      // super-tile id (16 blocks each)
    const int p   = tk & 15;                      // position in 4x4 super-tile
    const int snx = nx >> 2, sny = ny >> 2;
    const int zz  = S / (snx * sny);
    const int rS  = S - zz * (snx * sny);
    const int sy  = rS / snx;
    const int sx  = rS - sy * snx;
    const int yb  = sy * 4 + (p >> 2);
    const int xb  = sx * 4 + (p & 3);
    const long z  = zz;

    const long row0 = (long)yb * 128;
    const long col0 = (long)xb * 128;

    const int srow = (lane >> 3);                  // 0..7 within an 8-row chunk
    const int scol = ((lane & 7) ^ srow) * 8;      // swizzled col group this lane fetches

    const int ktiles = K >> 6;
    const int T = split * ktiles;

    const bf16* Az = A + z * bsA;
    const bf16* Bz = B + z * bsB;

    auto prefetch = [&](int ti, int buf) {
        const int ph = ti / ktiles;
        const int kt = (ti - ph * ktiles) << 6;
        const bf16* Ab = Az + (ph == 1 ? psA : 0);
        const bf16* Bb = Bz + (ph == 2 ? psB : 0);
#pragma unroll
        for (int p2 = 0; p2 < 4; ++p2) {
            const int chunk = wave * 32 + p2 * 8;   // 8 rows per 1KB wave store
            gld16(Ab + (row0 + chunk + srow) * lda + kt + scol, &As[buf][chunk * 64]);
            gld16(Bb + (col0 + chunk + srow) * ldb + kt + scol, &Bs[buf][chunk * 64]);
        }
    };

    f32x4 acc[4][4];
#pragma unroll
    for (int r = 0; r < 4; ++r)
#pragma unroll
        for (int c = 0; c < 4; ++c)
            acc[r][c] = (f32x4){0.f, 0.f, 0.f, 0.f};

    if constexpr (DBUF) {
        prefetch(0, 0);
        prefetch(1, 1);
        for (int ti = 0; ti < T; ++ti) {
            const int cur = ti & 1;
            if (ti + 1 < T) WAIT_VM8; else WAIT_VM0;   // oldest 8 (cur tile) landed
            __builtin_amdgcn_s_barrier();
            bf16x8 af[2][4], bg[2][4];
#pragma unroll
            for (int kk = 0; kk < 2; ++kk) {
                const int g0 = (kk << 2) + quad;
#pragma unroll
                for (int r = 0; r < 4; ++r)
                    af[kk][r] = *reinterpret_cast<const bf16x8*>(&As[cur][swz(wr * 64 + r * 16 + r16, g0)]);
#pragma unroll
                for (int c = 0; c < 4; ++c)
                    bg[kk][c] = *reinterpret_cast<const bf16x8*>(&Bs[cur][swz(wc * 64 + c * 16 + r16, g0)]);
            }
            WAIT_LGKM0;                                 // frags in regs
            __builtin_amdgcn_s_barrier();               // cur buffer free
            if (ti + 2 < T) prefetch(ti + 2, cur);
#pragma unroll
            for (int kk = 0; kk < 2; ++kk)
#pragma unroll
                for (int r = 0; r < 4; ++r)
#pragma unroll
                    for (int c = 0; c < 4; ++c)
                        acc[r][c] = __builtin_amdgcn_mfma_f32_16x16x32_bf16(af[kk][r], bg[kk][c], acc[r][c], 0, 0, 0);
        }
    } else {
        for (int ti = 0; ti < T; ++ti) {
            prefetch(ti, 0);
            __syncthreads();
#pragma unroll
            for (int kk = 0; kk < 2; ++kk) {
                const int g0 = (kk << 2) + quad;
                bf16x8 af[4], bg[4];
#pragma unroll
                for (int r = 0; r < 4; ++r)
                    af[r] = *reinterpret_cast<const bf16x8*>(&As[0][swz(wr * 64 + r * 16 + r16, g0)]);
#pragma unroll
                for (int c = 0; c < 4; ++c)
                    bg[c] = *reinterpret_cast<const bf16x8*>(&Bs[0][swz(wc * 64 + c * 16 + r16, g0)]);
#pragma unroll
                for (int r = 0; r < 4; ++r)
#pragma unroll
                    for (int c = 0; c < 4; ++c)
                        acc[r][c] = __builtin_amdgcn_mfma_f32_16x16x32_bf16(af[r], bg[c], acc[r][c], 0, 0, 0);
            }
            __syncthreads();
        }
    }

    const float scv = resid ? *scale : 0.f;

#pragma unroll
    for (int r = 0; r < 4; ++r) {
#pragma unroll
        for (int c = 0; c < 4; ++c) {
            long gcol = col0 + wc * 64 + c * 16 + r16;
            float bv = bias ? bias[gcol] : 0.f;
#pragma unroll
            for (int i = 0; i < 4; ++i) {
                long grow = row0 + wr * 64 + r * 16 + quad * 4 + i;
                float val = acc[r][c][i] + bv;
                if (mode == 0) {
                    if (resid) val += resid[z * bsR + grow * ldr + gcol] * scv;
                    ((float*)C)[z * bsC + grow * ldc + gcol] = val;
                } else if (mode == 1) {
                    if (resid) val += resid[z * bsR + grow * ldr + gcol] * scv;
                    bf16* Cb = (bf16*)C + z * bsC;
                    bf16 h = (bf16)val;
                    Cb[grow * ldc + gcol] = h;
                    Cb[psC + grow * ldc + gcol] = (bf16)(val - (float)h);
                } else {
                    long b = grow >> 11, s = grow & 2047;
                    bf16* Cb = (bf16*)C + b * bsC;
                    bf16 h = (bf16)val;
                    Cb[gcol * ldc + s] = h;
                    Cb[psC + gcol * ldc + s] = (bf16)(val - (float)h);
                }
            }
        }
    }
}

// Row softmax over 2048 f32 cols; writes P IN PLACE as bf16 hi plane (cols
// [0,2048) of the row's 4096 bf16 slots) and lo plane (cols [2048,4096)).
__global__ __launch_bounds__(256) void softmax_planes(float* __restrict__ S)
{
    __shared__ float redm[4], reds[4];
    float* srow = S + (long)blockIdx.x * 2048;
    const int t = threadIdx.x;
    const int lane = t & 63;
    const int wave = t >> 6;

    f32x4 v0 = *reinterpret_cast<const f32x4*>(srow + t * 4);
    f32x4 v1 = *reinterpret_cast<const f32x4*>(srow + 1024 + t * 4);

    float m = v0[0];
#pragma unroll
    for (int i = 1; i < 4; ++i) m = fmaxf(m, v0[i]);
#pragma unroll
    for (int i = 0; i < 4; ++i) m = fmaxf(m, v1[i]);
#pragma unroll
    for (int off = 32; off > 0; off >>= 1) m = fmaxf(m, __shfl_xor(m, off));
    if (lane == 0) redm[wave] = m;
    __syncthreads();
    m = fmaxf(fmaxf(redm[0], redm[1]), fmaxf(redm[2], redm[3]));

    float s = 0.f;
#pragma unroll
    for (int i = 0; i < 4; ++i) { v0[i] = __expf(v0[i] - m); s += v0[i]; }
#pragma unroll
    for (int i = 0; i < 4; ++i) { v1[i] = __expf(v1[i] - m); s += v1[i]; }
#pragma unroll
    for (int off = 32; off > 0; off >>= 1) s += __shfl_xor(s, off);
    if (lane == 0) reds[wave] = s;
    __syncthreads();
    s = reds[0] + reds[1] + reds[2] + reds[3];
    float inv = 1.f / s;

    bf16x4 h0, h1, l0, l1;
#pragma unroll
    for (int i = 0; i < 4; ++i) {
        float a = v0[i] * inv, b = v1[i] * inv;
        h0[i] = (bf16)a; l0[i] = (bf16)(a - (float)h0[i]);
        h1[i] = (bf16)b; l1[i] = (bf16)(b - (float)h1[i]);
    }
    bf16* ph = (bf16*)srow;
    *reinterpret_cast<bf16x4*>(ph + t * 4) = h0;
    *reinterpret_cast<bf16x4*>(ph + 1024 + t * 4) = h1;
    *reinterpret_cast<bf16x4*>(ph + 2048 + t * 4) = l0;
    *reinterpret_cast<bf16x4*>(ph + 3072 + t * 4) = l1;
}

// f32[n] -> hi bf16[n], lo bf16[n] (lo plane at hi+n). n % 1024 == 0.
__global__ __launch_bounds__(256) void split_f32(
    const float* __restrict__ in, bf16* __restrict__ hi, long n)
{
    long i = ((long)blockIdx.x * 256 + threadIdx.x) * 4;
    f32x4 v = *reinterpret_cast<const f32x4*>(in + i);
    bf16x4 h, l;
#pragma unroll
    for (int j = 0; j < 4; ++j) {
        h[j] = (bf16)v[j];
        l[j] = (bf16)(v[j] - (float)h[j]);
    }
    *reinterpret_cast<bf16x4*>(hi + i) = h;
    *reinterpret_cast<bf16x4*>(hi + n + i) = l;
}

extern "C" void kernel_launch(void* const* d_in, const int* in_sizes, int n_in,
                              void* d_out, int out_size, void* d_ws, size_t ws_size,
                              hipStream_t stream)
{
    const float* x   = (const float*)d_in[0];
    const float* y   = (const float*)d_in[1];
    const float* Wq1 = (const float*)d_in[2];
    const float* bq1 = (const float*)d_in[3];
    const float* Wk1 = (const float*)d_in[4];
    const float* bk1 = (const float*)d_in[5];
    const float* Wv1 = (const float*)d_in[6];
    const float* bv1 = (const float*)d_in[7];
    const float* Wq2 = (const float*)d_in[8];
    const float* bq2 = (const float*)d_in[9];
    const float* Wk2 = (const float*)d_in[10];
    const float* bk2 = (const float*)d_in[11];
    const float* Wv2 = (const float*)d_in[12];
    const float* bv2 = (const float*)d_in[13];
    const float* w1  = (const float*)d_in[14];
    const float* w2  = (const float*)d_in[15];
    float* out = (float*)d_out;

    const size_t MB = 1ull << 20;
    char* ws = (char*)d_ws;
    const long S = 2048, M4 = 8192, E1 = 512, E2 = 1024;
    const long W1ps = E1 * E1, W2ps = E2 * E2;

    const int cfg = (ws_size >= 207 * MB) ? 2 : 0;

    bf16 *Wq1p, *Wk1p, *Wv1p, *Wq2p, *Wk2p, *Wv2p, *temp, *qb, *kb, *vt;
    float* Sc;
    bf16* xp = (bf16*)d_out;             // [2][8192][512] planes (16MB), dead after stage-1 proj
    bf16* yp = xp + 2 * M4 * E1;
    if (cfg == 2) {
        Wq1p = (bf16*)(ws + 0 * MB);  Wk1p = (bf16*)(ws + 1 * MB);  Wv1p = (bf16*)(ws + 2 * MB);
        Wq2p = (bf16*)(ws + 3 * MB);  Wk2p = (bf16*)(ws + 7 * MB);  Wv2p = (bf16*)(ws + 11 * MB);
        temp = (bf16*)(ws + 15 * MB);                 // [2][8192][1024] 32MB
        qb   = (bf16*)(ws + 47 * MB);                 // [2][8192][E]   32MB
        kb   = (bf16*)(ws + 79 * MB);
        vt   = (bf16*)(ws + 111 * MB);                // [4][2][E][2048] 32MB
        Sc   = (float*)(ws + 143 * MB);               // [4][2048][2048] 64MB
    } else {
        Wq1p = (bf16*)(ws + 0 * MB);  Wk1p = (bf16*)(ws + 1 * MB);  Wv1p = (bf16*)(ws + 2 * MB);
        temp = (bf16*)(ws + 3 * MB);
        qb   = (bf16*)(ws + 35 * MB);
        kb   = (bf16*)(ws + 43 * MB);
        vt   = (bf16*)(ws + 51 * MB);
        Sc   = (float*)(ws + 59 * MB);
        Wq2p = (bf16*)d_out;
        Wk2p = Wq2p + 2 * W2ps;
        Wv2p = Wk2p + 2 * W2ps;
    }

    // db=true -> double-buffered kernel (for 1-block/CU dispatches: proj, PV)
    auto gemm = [&](const bf16* A, long lda, long psA, long bsA,
                    const bf16* B, long ldb, long psB, long bsB,
                    void* C, long ldc, long psC, long bsC, int mode,
                    const float* bias, const float* resid, long ldr, long bsR,
                    const float* scale, int M, int N, int K, int split, int gz,
                    bool db) {
        int nx = N / 128, ny = M / 128;
        dim3 g((unsigned)(nx * ny * gz));
        if (db)
            gemm_split<true><<<g, dim3(256), 0, stream>>>(
                A, lda, psA, bsA, B, ldb, psB, bsB, C, ldc, psC, bsC, mode,
                bias, resid, ldr, bsR, scale, K, split, nx, ny);
        else
            gemm_split<false><<<g, dim3(256), 0, stream>>>(
                A, lda, psA, bsA, B, ldb, psB, bsB, C, ldc, psC, bsC, mode,
                bias, resid, ldr, bsR, scale, K, split, nx, ny);
    };
    auto conv = [&](const float* in, bf16* planes, long n) {
        split_f32<<<dim3((unsigned)(n / 1024)), dim3(256), 0, stream>>>(in, planes, n);
    };

    conv(x, xp, M4 * E1);
    conv(y, yp, M4 * E1);
    conv(Wq1, Wq1p, W1ps); conv(Wk1, Wk1p, W1ps); conv(Wv1, Wv1p, W1ps);
    if (cfg == 2) { conv(Wq2, Wq2p, W2ps); conv(Wk2, Wk2p, W2ps); conv(Wv2, Wv2p, W2ps); }

    auto stage1 = [&](const bf16* sp, const float* resid, const float* scale, long colOff) {
        if (cfg == 2) {
            gemm(sp, E1, M4 * E1, 0, Wq1p, E1, W1ps, 0, qb, E1, M4 * E1, 0, 1,
                 bq1, nullptr, 0, 0, nullptr, 8192, 512, 512, 3, 1, true);
            gemm(sp, E1, M4 * E1, 0, Wk1p, E1, W1ps, 0, kb, E1, M4 * E1, 0, 1,
                 bk1, nullptr, 0, 0, nullptr, 8192, 512, 512, 3, 1, true);
            gemm(sp, E1, M4 * E1, 0, Wv1p, E1, W1ps, 0, vt, S, E1 * S, 2 * E1 * S, 2,
                 bv1, nullptr, 0, 0, nullptr, 8192, 512, 512, 3, 1, true);
            gemm(qb, E1, M4 * E1, S * E1, kb, E1, M4 * E1, S * E1, Sc, S, 0, S * S, 0,
                 nullptr, nullptr, 0, 0, nullptr, 2048, 2048, 512, 3, 4, false);
            softmax_planes<<<dim3(8192), dim3(256), 0, stream>>>(Sc);
            gemm((const bf16*)Sc, 4096, 2048, S * 4096, vt, S, E1 * S, 2 * E1 * S,
                 temp + colOff, 1024, M4 * 1024, S * 1024, 1,
                 nullptr, resid, E1, S * E1, scale, 2048, 512, 2048, 3, 4, true);
        } else {
            for (int b = 0; b < 4; ++b) {
                const bf16* sb = sp + (long)b * S * E1;
                gemm(sb, E1, M4 * E1, 0, Wq1p, E1, W1ps, 0, qb, E1, S * E1, 0, 1,
                     bq1, nullptr, 0, 0, nullptr, 2048, 512, 512, 3, 1, true);
                gemm(sb, E1, M4 * E1, 0, Wk1p, E1, W1ps, 0, kb, E1, S * E1, 0, 1,
                     bk1, nullptr, 0, 0, nullptr, 2048, 512, 512, 3, 1, true);
                gemm(sb, E1, M4 * E1, 0, Wv1p, E1, W1ps, 0, vt, S, E1 * S, 0, 2,
                     bv1, nullptr, 0, 0, nullptr, 2048, 512, 512, 3, 1, true);
                gemm(qb, E1, S * E1, 0, kb, E1, S * E1, 0, Sc, S, 0, 0, 0,
                     nullptr, nullptr, 0, 0, nullptr, 2048, 2048, 512, 3, 1, false);
                softmax_planes<<<dim3(2048), dim3(256), 0, stream>>>(Sc);
                gemm((const bf16*)Sc, 4096, 2048, 0, vt, S, E1 * S, 0,
                     temp + colOff + (long)b * S * 1024, 1024, M4 * 1024, 0, 1,
                     nullptr, resid + (long)b * S * E1, E1, 0, scale, 2048, 512, 2048, 3, 1, true);
            }
        }
    };

    stage1(xp, y, w2, 0);     // x1 = attn(x) + y*weight2
    stage1(yp, x, w1, 512);   // y1 = attn(y) + x*weight1

    if (cfg == 0) { conv(Wq2, Wq2p, W2ps); conv(Wk2, Wk2p, W2ps); conv(Wv2, Wv2p, W2ps); }

    if (cfg == 2) {
        gemm(temp, E2, M4 * E2, 0, Wq2p, E2, W2ps, 0, qb, E2, M4 * E2, 0, 1,
             bq2, nullptr, 0, 0, nullptr, 8192, 1024, 1024, 3, 1, true);
        gemm(temp, E2, M4 * E2, 0, Wk2p, E2, W2ps, 0, kb, E2, M4 * E2, 0, 1,
             bk2, nullptr, 0, 0, nullptr, 8192, 1024, 1024, 3, 1, true);
        gemm(temp, E2, M4 * E2, 0, Wv2p, E2, W2ps, 0, vt, S, E2 * S, 2 * E2 * S, 2,
             bv2, nullptr, 0, 0, nullptr, 8192, 1024, 1024, 1, 1, true);
        gemm(qb, E2, M4 * E2, S * E2, kb, E2, M4 * E2, S * E2, Sc, S, 0, S * S, 0,
             nullptr, nullptr, 0, 0, nullptr, 2048, 2048, 1024, 3, 4, false);
        softmax_planes<<<dim3(8192), dim3(256), 0, stream>>>(Sc);
        gemm((const bf16*)Sc, 4096, 2048, S * 4096, vt, S, E2 * S, 2 * E2 * S,
             out, E2, 0, S * E2, 0, nullptr, nullptr, 0, 0, nullptr,
             2048, 1024, 2048, 1, 4, true);
    } else {
        for (int b = 0; b < 4; ++b) {
            const bf16* tb = temp + (long)b * S * E2;
            gemm(tb, E2, M4 * E2, 0, Wq2p, E2, W2ps, 0, qb, E2, S * E2, 0, 1,
                 bq2, nullptr, 0, 0, nullptr, 2048, 1024, 1024, 3, 1, true);
            gemm(tb, E2, M4 * E2, 0, Wk2p, E2, W2ps, 0, kb, E2, S * E2, 0, 1,
                 bk2, nullptr, 0, 0, nullptr, 2048, 1024, 1024, 3, 1, true);
            gemm(tb, E2, M4 * E2, 0, Wv2p, E2, W2ps, 0, vt, S, E2 * S, 0, 2,
                 bv2, nullptr, 0, 0, nullptr, 2048, 1024, 1024, 1, 1, true);
            gemm(qb, E2, S * E2, 0, kb, E2, S * E2, 0, Sc, S, 0, 0, 0,
                 nullptr, nullptr, 0, 0, nullptr, 2048, 2048, 1024, 3, 1, false);
            softmax_planes<<<dim3(2048), dim3(256), 0, stream>>>(Sc);
            gemm((const bf16*)Sc, 4096, 2048, 0, vt, S, E2 * S, 0,
                 out + (long)b * S * E2, E2, 0, 0, 0, nullptr, nullptr, 0, 0, nullptr,
                 2048, 1024, 2048, 1, 1, true);
        }
    }

    (void)in_sizes; (void)n_in; (void)out_size;
}

// Round 8
// 1027.328 us; speedup vs baseline: 4.6425x; 1.0706x over previous
//
#include <hip/hip_runtime.h>
#include <hip/hip_bf16.h>
#include <cstdint>
#include <cstddef>

// Cross_attention_dl: B=4, S=2048, D1=512, D2=1024. ALL I/O f32.
// Split-precision (bf16 hi/lo plane) MFMA pipeline; operands pre-split in
// global. Round 8: (a) double-buffered K-loop for ALL gemms (scores were the
// last single-buffered dispatches, serialization-bound at 322 TF),
// (b) contiguous per-XCD supertile chunks (A-row reuse across supertiles).

typedef __bf16 bf16;
typedef __attribute__((ext_vector_type(8))) __bf16 bf16x8;
typedef __attribute__((ext_vector_type(4))) __bf16 bf16x4;
typedef __attribute__((ext_vector_type(4))) float f32x4;

__device__ __forceinline__ void gld16(const bf16* g, bf16* s) {
    __builtin_amdgcn_global_load_lds(
        (const __attribute__((address_space(1))) void*)g,
        (__attribute__((address_space(3))) void*)s, 16, 0, 0);
}

// gfx9 waitcnt imm: vmcnt[3:0]+[15:14], expcnt[6:4], lgkmcnt[11:8]
#define WAIT_VM8   __builtin_amdgcn_s_waitcnt(8 | (7 << 4) | (0xF << 8))
#define WAIT_VM0   __builtin_amdgcn_s_waitcnt(0 | (7 << 4) | (0xF << 8))
#define WAIT_LGKM0 __builtin_amdgcn_s_waitcnt(0xF | (7 << 4) | (0 << 8) | (3 << 14))

// element offset of logical (row, col-group g) in a swizzled [128][64] tile
__device__ __forceinline__ int swz(int row, int g) {
    return row * 64 + ((g ^ (row & 7)) << 3);
}

// C = A @ B^T over bf16 planes. All strides in ELEMENTS. Flat 1-D grid with
// XCD supertile decode: xcd = g&7 owns a CONTIGUOUS chunk of 4x4 (y,x)
// supertiles (16 blocks each); consecutive supertiles share sy => A-strip
// reuse in that XCD's L2. Requires grid % 128 == 0.
// split=3: phases (A0,B0),(A1,B0),(A0,B1); split=1: (A0,B0) only.
// mode 0: f32 C[z][m][n] = acc (+resid*scale)
// mode 1: bf16 plane-pair row-major: C[p][z*M+m][n] = acc + bias[n] (+resid*scale)
// mode 2: bf16 plane-pair transposed: C[b][p][n][s] (b=grow>>11, s=grow&2047)
__global__ __launch_bounds__(256) void gemm_split(
    const bf16* __restrict__ A, long lda, long psA, long bsA,
    const bf16* __restrict__ B, long ldb, long psB, long bsB,
    void* __restrict__ C, long ldc, long psC, long bsC, int mode,
    const float* __restrict__ bias,
    const float* __restrict__ resid, long ldr, long bsR,
    const float* __restrict__ scale,
    int K, int split, int nx, int ny)
{
    __shared__ __align__(16) bf16 As[2][128 * 64];
    __shared__ __align__(16) bf16 Bs[2][128 * 64];

    const int t    = threadIdx.x;
    const int wave = t >> 6;
    const int lane = t & 63;
    const int wr   = wave >> 1;
    const int wc   = wave & 1;
    const int r16  = lane & 15;
    const int quad = lane >> 4;

    // contiguous-chunk supertile decode
    const int g    = blockIdx.x;
    const int xcd  = g & 7;
    const int tk   = g >> 3;
    const int nst8 = gridDim.x >> 7;              // supertiles per XCD
    const int st   = xcd * nst8 + (tk >> 4);      // global supertile id
    const int p    = tk & 15;                     // position in 4x4 supertile
    const int snx  = nx >> 2, sny = ny >> 2;
    const int spz  = snx * sny;
    const int zz   = st / spz;
    const int rS   = st - zz * spz;
    const int sy   = rS / snx;
    const int sx   = rS - sy * snx;
    const int yb   = sy * 4 + (p >> 2);
    const int xb   = sx * 4 + (p & 3);
    const long z   = zz;

    const long row0 = (long)yb * 128;
    const long col0 = (long)xb * 128;

    const int srow = (lane >> 3);                  // 0..7 within an 8-row chunk
    const int scol = ((lane & 7) ^ srow) * 8;      // swizzled col group this lane fetches

    const int ktiles = K >> 6;
    const int T = split * ktiles;

    const bf16* Az = A + z * bsA;
    const bf16* Bz = B + z * bsB;

    auto prefetch = [&](int ti, int buf) {
        const int ph = ti / ktiles;
        const int kt = (ti - ph * ktiles) << 6;
        const bf16* Ab = Az + (ph == 1 ? psA : 0);
        const bf16* Bb = Bz + (ph == 2 ? psB : 0);
#pragma unroll
        for (int p2 = 0; p2 < 4; ++p2) {
            const int chunk = wave * 32 + p2 * 8;   // 8 rows per 1KB wave store
            gld16(Ab + (row0 + chunk + srow) * lda + kt + scol, &As[buf][chunk * 64]);
            gld16(Bb + (col0 + chunk + srow) * ldb + kt + scol, &Bs[buf][chunk * 64]);
        }
    };

    f32x4 acc[4][4];
#pragma unroll
    for (int r = 0; r < 4; ++r)
#pragma unroll
        for (int c = 0; c < 4; ++c)
            acc[r][c] = (f32x4){0.f, 0.f, 0.f, 0.f};

    prefetch(0, 0);
    prefetch(1, 1);
    for (int ti = 0; ti < T; ++ti) {
        const int cur = ti & 1;
        if (ti + 1 < T) WAIT_VM8; else WAIT_VM0;   // oldest 8 (cur tile) landed
        __builtin_amdgcn_s_barrier();
        bf16x8 af[2][4], bg[2][4];
#pragma unroll
        for (int kk = 0; kk < 2; ++kk) {
            const int g0 = (kk << 2) + quad;
#pragma unroll
            for (int r = 0; r < 4; ++r)
                af[kk][r] = *reinterpret_cast<const bf16x8*>(&As[cur][swz(wr * 64 + r * 16 + r16, g0)]);
#pragma unroll
            for (int c = 0; c < 4; ++c)
                bg[kk][c] = *reinterpret_cast<const bf16x8*>(&Bs[cur][swz(wc * 64 + c * 16 + r16, g0)]);
        }
        WAIT_LGKM0;                                 // frags in regs
        __builtin_amdgcn_s_barrier();               // cur buffer free
        if (ti + 2 < T) prefetch(ti + 2, cur);
#pragma unroll
        for (int kk = 0; kk < 2; ++kk)
#pragma unroll
            for (int r = 0; r < 4; ++r)
#pragma unroll
                for (int c = 0; c < 4; ++c)
                    acc[r][c] = __builtin_amdgcn_mfma_f32_16x16x32_bf16(af[kk][r], bg[kk][c], acc[r][c], 0, 0, 0);
    }

    const float scv = resid ? *scale : 0.f;

#pragma unroll
    for (int r = 0; r < 4; ++r) {
#pragma unroll
        for (int c = 0; c < 4; ++c) {
            long gcol = col0 + wc * 64 + c * 16 + r16;
            float bv = bias ? bias[gcol] : 0.f;
#pragma unroll
            for (int i = 0; i < 4; ++i) {
                long grow = row0 + wr * 64 + r * 16 + quad * 4 + i;
                float val = acc[r][c][i] + bv;
                if (mode == 0) {
                    if (resid) val += resid[z * bsR + grow * ldr + gcol] * scv;
                    ((float*)C)[z * bsC + grow * ldc + gcol] = val;
                } else if (mode == 1) {
                    if (resid) val += resid[z * bsR + grow * ldr + gcol] * scv;
                    bf16* Cb = (bf16*)C + z * bsC;
                    bf16 h = (bf16)val;
                    Cb[grow * ldc + gcol] = h;
                    Cb[psC + grow * ldc + gcol] = (bf16)(val - (float)h);
                } else {
                    long b = grow >> 11, s = grow & 2047;
                    bf16* Cb = (bf16*)C + b * bsC;
                    bf16 h = (bf16)val;
                    Cb[gcol * ldc + s] = h;
                    Cb[psC + gcol * ldc + s] = (bf16)(val - (float)h);
                }
            }
        }
    }
}

// Row softmax over 2048 f32 cols; writes P IN PLACE as bf16 hi plane (cols
// [0,2048) of the row's 4096 bf16 slots) and lo plane (cols [2048,4096)).
__global__ __launch_bounds__(256) void softmax_planes(float* __restrict__ S)
{
    __shared__ float redm[4], reds[4];
    float* srow = S + (long)blockIdx.x * 2048;
    const int t = threadIdx.x;
    const int lane = t & 63;
    const int wave = t >> 6;

    f32x4 v0 = *reinterpret_cast<const f32x4*>(srow + t * 4);
    f32x4 v1 = *reinterpret_cast<const f32x4*>(srow + 1024 + t * 4);

    float m = v0[0];
#pragma unroll
    for (int i = 1; i < 4; ++i) m = fmaxf(m, v0[i]);
#pragma unroll
    for (int i = 0; i < 4; ++i) m = fmaxf(m, v1[i]);
#pragma unroll
    for (int off = 32; off > 0; off >>= 1) m = fmaxf(m, __shfl_xor(m, off));
    if (lane == 0) redm[wave] = m;
    __syncthreads();
    m = fmaxf(fmaxf(redm[0], redm[1]), fmaxf(redm[2], redm[3]));

    float s = 0.f;
#pragma unroll
    for (int i = 0; i < 4; ++i) { v0[i] = __expf(v0[i] - m); s += v0[i]; }
#pragma unroll
    for (int i = 0; i < 4; ++i) { v1[i] = __expf(v1[i] - m); s += v1[i]; }
#pragma unroll
    for (int off = 32; off > 0; off >>= 1) s += __shfl_xor(s, off);
    if (lane == 0) reds[wave] = s;
    __syncthreads();
    s = reds[0] + reds[1] + reds[2] + reds[3];
    float inv = 1.f / s;

    bf16x4 h0, h1, l0, l1;
#pragma unroll
    for (int i = 0; i < 4; ++i) {
        float a = v0[i] * inv, b = v1[i] * inv;
        h0[i] = (bf16)a; l0[i] = (bf16)(a - (float)h0[i]);
        h1[i] = (bf16)b; l1[i] = (bf16)(b - (float)h1[i]);
    }
    bf16* ph = (bf16*)srow;
    *reinterpret_cast<bf16x4*>(ph + t * 4) = h0;
    *reinterpret_cast<bf16x4*>(ph + 1024 + t * 4) = h1;
    *reinterpret_cast<bf16x4*>(ph + 2048 + t * 4) = l0;
    *reinterpret_cast<bf16x4*>(ph + 3072 + t * 4) = l1;
}

// f32[n] -> hi bf16[n], lo bf16[n] (lo plane at hi+n). n % 1024 == 0.
__global__ __launch_bounds__(256) void split_f32(
    const float* __restrict__ in, bf16* __restrict__ hi, long n)
{
    long i = ((long)blockIdx.x * 256 + threadIdx.x) * 4;
    f32x4 v = *reinterpret_cast<const f32x4*>(in + i);
    bf16x4 h, l;
#pragma unroll
    for (int j = 0; j < 4; ++j) {
        h[j] = (bf16)v[j];
        l[j] = (bf16)(v[j] - (float)h[j]);
    }
    *reinterpret_cast<bf16x4*>(hi + i) = h;
    *reinterpret_cast<bf16x4*>(hi + n + i) = l;
}

extern "C" void kernel_launch(void* const* d_in, const int* in_sizes, int n_in,
                              void* d_out, int out_size, void* d_ws, size_t ws_size,
                              hipStream_t stream)
{
    const float* x   = (const float*)d_in[0];
    const float* y   = (const float*)d_in[1];
    const float* Wq1 = (const float*)d_in[2];
    const float* bq1 = (const float*)d_in[3];
    const float* Wk1 = (const float*)d_in[4];
    const float* bk1 = (const float*)d_in[5];
    const float* Wv1 = (const float*)d_in[6];
    const float* bv1 = (const float*)d_in[7];
    const float* Wq2 = (const float*)d_in[8];
    const float* bq2 = (const float*)d_in[9];
    const float* Wk2 = (const float*)d_in[10];
    const float* bk2 = (const float*)d_in[11];
    const float* Wv2 = (const float*)d_in[12];
    const float* bv2 = (const float*)d_in[13];
    const float* w1  = (const float*)d_in[14];
    const float* w2  = (const float*)d_in[15];
    float* out = (float*)d_out;

    const size_t MB = 1ull << 20;
    char* ws = (char*)d_ws;
    const long S = 2048, M4 = 8192, E1 = 512, E2 = 1024;
    const long W1ps = E1 * E1, W2ps = E2 * E2;

    const int cfg = (ws_size >= 207 * MB) ? 2 : 0;

    bf16 *Wq1p, *Wk1p, *Wv1p, *Wq2p, *Wk2p, *Wv2p, *temp, *qb, *kb, *vt;
    float* Sc;
    bf16* xp = (bf16*)d_out;             // [2][8192][512] planes (16MB), dead after stage-1 proj
    bf16* yp = xp + 2 * M4 * E1;
    if (cfg == 2) {
        Wq1p = (bf16*)(ws + 0 * MB);  Wk1p = (bf16*)(ws + 1 * MB);  Wv1p = (bf16*)(ws + 2 * MB);
        Wq2p = (bf16*)(ws + 3 * MB);  Wk2p = (bf16*)(ws + 7 * MB);  Wv2p = (bf16*)(ws + 11 * MB);
        temp = (bf16*)(ws + 15 * MB);                 // [2][8192][1024] 32MB
        qb   = (bf16*)(ws + 47 * MB);                 // [2][8192][E]   32MB
        kb   = (bf16*)(ws + 79 * MB);
        vt   = (bf16*)(ws + 111 * MB);                // [4][2][E][2048] 32MB
        Sc   = (float*)(ws + 143 * MB);               // [4][2048][2048] 64MB
    } else {
        Wq1p = (bf16*)(ws + 0 * MB);  Wk1p = (bf16*)(ws + 1 * MB);  Wv1p = (bf16*)(ws + 2 * MB);
        temp = (bf16*)(ws + 3 * MB);
        qb   = (bf16*)(ws + 35 * MB);
        kb   = (bf16*)(ws + 43 * MB);
        vt   = (bf16*)(ws + 51 * MB);
        Sc   = (float*)(ws + 59 * MB);
        Wq2p = (bf16*)d_out;
        Wk2p = Wq2p + 2 * W2ps;
        Wv2p = Wk2p + 2 * W2ps;
    }

    auto gemm = [&](const bf16* A, long lda, long psA, long bsA,
                    const bf16* B, long ldb, long psB, long bsB,
                    void* C, long ldc, long psC, long bsC, int mode,
                    const float* bias, const float* resid, long ldr, long bsR,
                    const float* scale, int M, int N, int K, int split, int gz) {
        int nx = N / 128, ny = M / 128;
        dim3 g((unsigned)(nx * ny * gz));
        gemm_split<<<g, dim3(256), 0, stream>>>(
            A, lda, psA, bsA, B, ldb, psB, bsB, C, ldc, psC, bsC, mode,
            bias, resid, ldr, bsR, scale, K, split, nx, ny);
    };
    auto conv = [&](const float* in, bf16* planes, long n) {
        split_f32<<<dim3((unsigned)(n / 1024)), dim3(256), 0, stream>>>(in, planes, n);
    };

    conv(x, xp, M4 * E1);
    conv(y, yp, M4 * E1);
    conv(Wq1, Wq1p, W1ps); conv(Wk1, Wk1p, W1ps); conv(Wv1, Wv1p, W1ps);
    if (cfg == 2) { conv(Wq2, Wq2p, W2ps); conv(Wk2, Wk2p, W2ps); conv(Wv2, Wv2p, W2ps); }

    auto stage1 = [&](const bf16* sp, const float* resid, const float* scale, long colOff) {
        if (cfg == 2) {
            gemm(sp, E1, M4 * E1, 0, Wq1p, E1, W1ps, 0, qb, E1, M4 * E1, 0, 1,
                 bq1, nullptr, 0, 0, nullptr, 8192, 512, 512, 3, 1);
            gemm(sp, E1, M4 * E1, 0, Wk1p, E1, W1ps, 0, kb, E1, M4 * E1, 0, 1,
                 bk1, nullptr, 0, 0, nullptr, 8192, 512, 512, 3, 1);
            gemm(sp, E1, M4 * E1, 0, Wv1p, E1, W1ps, 0, vt, S, E1 * S, 2 * E1 * S, 2,
                 bv1, nullptr, 0, 0, nullptr, 8192, 512, 512, 3, 1);
            gemm(qb, E1, M4 * E1, S * E1, kb, E1, M4 * E1, S * E1, Sc, S, 0, S * S, 0,
                 nullptr, nullptr, 0, 0, nullptr, 2048, 2048, 512, 3, 4);
            softmax_planes<<<dim3(8192), dim3(256), 0, stream>>>(Sc);
            gemm((const bf16*)Sc, 4096, 2048, S * 4096, vt, S, E1 * S, 2 * E1 * S,
                 temp + colOff, 1024, M4 * 1024, S * 1024, 1,
                 nullptr, resid, E1, S * E1, scale, 2048, 512, 2048, 3, 4);
        } else {
            for (int b = 0; b < 4; ++b) {
                const bf16* sb = sp + (long)b * S * E1;
                gemm(sb, E1, M4 * E1, 0, Wq1p, E1, W1ps, 0, qb, E1, S * E1, 0, 1,
                     bq1, nullptr, 0, 0, nullptr, 2048, 512, 512, 3, 1);
                gemm(sb, E1, M4 * E1, 0, Wk1p, E1, W1ps, 0, kb, E1, S * E1, 0, 1,
                     bk1, nullptr, 0, 0, nullptr, 2048, 512, 512, 3, 1);
                gemm(sb, E1, M4 * E1, 0, Wv1p, E1, W1ps, 0, vt, S, E1 * S, 0, 2,
                     bv1, nullptr, 0, 0, nullptr, 2048, 512, 512, 3, 1);
                gemm(qb, E1, S * E1, 0, kb, E1, S * E1, 0, Sc, S, 0, 0, 0,
                     nullptr, nullptr, 0, 0, nullptr, 2048, 2048, 512, 3, 1);
                softmax_planes<<<dim3(2048), dim3(256), 0, stream>>>(Sc);
                gemm((const bf16*)Sc, 4096, 2048, 0, vt, S, E1 * S, 0,
                     temp + colOff + (long)b * S * 1024, 1024, M4 * 1024, 0, 1,
                     nullptr, resid + (long)b * S * E1, E1, 0, scale, 2048, 512, 2048, 3, 1);
            }
        }
    };

    stage1(xp, y, w2, 0);     // x1 = attn(x) + y*weight2
    stage1(yp, x, w1, 512);   // y1 = attn(y) + x*weight1

    if (cfg == 0) { conv(Wq2, Wq2p, W2ps); conv(Wk2, Wk2p, W2ps); conv(Wv2, Wv2p, W2ps); }

    if (cfg == 2) {
        gemm(temp, E2, M4 * E2, 0, Wq2p, E2, W2ps, 0, qb, E2, M4 * E2, 0, 1,
             bq2, nullptr, 0, 0, nullptr, 8192, 1024, 1024, 3, 1);
        gemm(temp, E2, M4 * E2, 0, Wk2p, E2, W2ps, 0, kb, E2, M4 * E2, 0, 1,
             bk2, nullptr, 0, 0, nullptr, 8192, 1024, 1024, 3, 1);
        gemm(temp, E2, M4 * E2, 0, Wv2p, E2, W2ps, 0, vt, S, E2 * S, 2 * E2 * S, 2,
             bv2, nullptr, 0, 0, nullptr, 8192, 1024, 1024, 1, 1);
        gemm(qb, E2, M4 * E2, S * E2, kb, E2, M4 * E2, S * E2, Sc, S, 0, S * S, 0,
             nullptr, nullptr, 0, 0, nullptr, 2048, 2048, 1024, 3, 4);
        softmax_planes<<<dim3(8192), dim3(256), 0, stream>>>(Sc);
        gemm((const bf16*)Sc, 4096, 2048, S * 4096, vt, S, E2 * S, 2 * E2 * S,
             out, E2, 0, S * E2, 0, nullptr, nullptr, 0, 0, nullptr,
             2048, 1024, 2048, 1, 4);
    } else {
        for (int b = 0; b < 4; ++b) {
            const bf16* tb = temp + (long)b * S * E2;
            gemm(tb, E2, M4 * E2, 0, Wq2p, E2, W2ps, 0, qb, E2, S * E2, 0, 1,
                 bq2, nullptr, 0, 0, nullptr, 2048, 1024, 1024, 3, 1);
            gemm(tb, E2, M4 * E2, 0, Wk2p, E2, W2ps, 0, kb, E2, S * E2, 0, 1,
                 bk2, nullptr, 0, 0, nullptr, 2048, 1024, 1024, 3, 1);
            gemm(tb, E2, M4 * E2, 0, Wv2p, E2, W2ps, 0, vt, S, E2 * S, 0, 2,
                 bv2, nullptr, 0, 0, nullptr, 2048, 1024, 1024, 1, 1);
            gemm(qb, E2, S * E2, 0, kb, E2, S * E2, 0, Sc, S, 0, 0, 0,
                 nullptr, nullptr, 0, 0, nullptr, 2048, 2048, 1024, 3, 1);
            softmax_planes<<<dim3(2048), dim3(256), 0, stream>>>(Sc);
            gemm((const bf16*)Sc, 4096, 2048, 0, vt, S, E2 * S, 0,
                 out + (long)b * S * E2, E2, 0, 0, 0, nullptr, nullptr, 0, 0, nullptr,
                 2048, 1024, 2048, 1, 1);
        }
    }

    (void)in_sizes; (void)n_in; (void)out_size;
}